// Round 17
// baseline (449.852 us; speedup 1.0000x reference)
//
#include <hip/hip_runtime.h>

// GrCNN: B=32, L=128, D=256, 127 sequential levels.
// Round 17: = round 16 (passed, 449us; bit-identical compute to r15) with the
// in-block sync cost cut -- computation still bit-identical:
//  - RAW BARRIERS: MID and END become "s_waitcnt lgkmcnt(0); s_barrier"
//    (memory-clobber asm). Neither needs vmcnt(0): MID orders only LDS
//    (pexch/gbuf), END orders only LDS (wo rows + import row). Exports get
//    their own per-wave vmcnt(0) before the early flag (kept from r16);
//    pmax has no intra-kernel consumer. Removes 2 global-drain stalls/level.
//  - GATE BROADCAST VIA LDS: the 12 ds_bpermute shfls (g0/g1/g2 x 4 rows)
//    become 3 ds_write_b32 (lanes<16) + lgkmcnt(0) + 3 broadcast
//    ds_read_b128 from a per-wave sgbuf slice. Same bits, half the LDS ops.
// K-split pairing, fp32 carries, pinned W (AGPR-resident), ring-4 flag/ack,
// overlapped import, pmax+decode identical to r15/r16.

#define B_ 32
#define L_ 128
#define D_ 256
#define NTHR 512
#define BUFB 16384
#define GBUF 25088            // gbuf: [w][16] f32x4 = 2048 B
#define PEX  27136            // pexch: [g][tile][lane] f32x4 = 16384 B
#define SGB  43520            // sgbuf: [w][16][3] float = 1536 B
#define LOG2E 1.4426950408889634f
#define PS_SLOTS 568          // sum_{h=0}^{7} (127-16h)

typedef _Float16 half8 __attribute__((ext_vector_type(8)));
typedef float f32x4 __attribute__((ext_vector_type(4)));
typedef unsigned u32x4 __attribute__((ext_vector_type(4)));

#define SWZ(o)  ((o) ^ ((((o) >> 9) & 7) << 4))
#define MFMA16 __builtin_amdgcn_mfma_f32_16x16x32_f16
// LDS-only barrier: no vmcnt drain (exports/pmax ordered separately)
#define LDS_BARRIER() asm volatile("s_waitcnt lgkmcnt(0)\n\ts_barrier" ::: "memory")

// 32-bit-component register pin (r13-verified: stays resident, no remat)
#define PIN(H) { \
    u32x4 t_ = __builtin_bit_cast(u32x4, H); \
    unsigned p0_ = t_[0], p1_ = t_[1], p2_ = t_[2], p3_ = t_[3]; \
    asm volatile("" : "+v"(p0_), "+v"(p1_), "+v"(p2_), "+v"(p3_)); \
    t_[0] = p0_; t_[1] = p1_; t_[2] = p2_; t_[3] = p3_; \
    H = __builtin_bit_cast(half8, t_); }

// ---- WT[272][512] fp16: col j -> 512 k (k<256: Wl/Gl row k, else Wr/Gr) ----
__global__ void prep_wt(const float* __restrict__ Wl, const float* __restrict__ Wr,
                        const float* __restrict__ Gl, const float* __restrict__ Gr,
                        _Float16* __restrict__ WT) {
    int j = blockIdx.x;
    for (int k = threadIdx.x; k < 512; k += 256) {
        float v = 0.f;
        if (j < 256) v = (k < 256) ? Wl[k * 256 + j] : Wr[(k - 256) * 256 + j];
        else { int jj = j - 256; if (jj < 3) v = (k < 256) ? Gl[k * 3 + jj] : Gr[(k - 256) * 3 + jj]; }
        WT[(size_t)j * 512 + k] = (_Float16)v;
    }
}

// ---- init: zero flags+acks, level-0 col max ----
__global__ void init_misc(const float* __restrict__ x, float* __restrict__ out,
                          int* __restrict__ flags) {
    int b = blockIdx.x, c = threadIdx.x;
    if (b == 0) for (int i = c; i < 2 * 256 * 16; i += 256) flags[i] = 0;
    float m = -3.4e38f;
    for (int row = 0; row < L_; ++row)
        m = fmaxf(m, x[((size_t)b * L_ + row) * D_ + c]);
    out[(size_t)b * L_ * D_ + c] = m;
}

// ---- decode: pmax partials -> out levels 1..127 (col map for K-split waves) ----
__global__ void decode_out(const unsigned* __restrict__ pmax, float* __restrict__ out) {
    for (size_t i = (size_t)blockIdx.x * 256 + threadIdx.x; i < (size_t)32 * 127 * 256;
         i += (size_t)gridDim.x * 256) {
        int c = (int)(i & 255);
        int k = (int)((i >> 8) % 127) + 1;
        int b = (int)(i / (127 * 256));
        int hcnt = (143 - k) >> 4;              // ceil((128-k)/16)
        // c = 64g + 32khalf + 16NT + lr; w = 4khalf+g; dw = w*16+lr
        int dw = ((c >> 5) & 1) * 64 + ((c >> 6) & 3) * 16 + (c & 15);
        int hi = (c >> 4) & 1;                  // NT
        float mx = -3.4e38f;
        for (int h = 0; h < hcnt; ++h) {
            int slot = 127 * h - 8 * h * (h - 1) + (k - 1);
            unsigned u = pmax[((size_t)b * PS_SLOTS + slot) * 128 + dw];
            unsigned short us = hi ? (unsigned short)(u >> 16) : (unsigned short)(u & 0xffff);
            float v = (float)__builtin_bit_cast(_Float16, us);
            mx = fmaxf(mx, v);
        }
        out[((size_t)b * 128 + k) * 256 + c] = mx;
    }
}

__global__ __launch_bounds__(NTHR, 2) void grcnn_main(
    const float* __restrict__ x, const _Float16* __restrict__ WT,
    const float* __restrict__ Wb, const float* __restrict__ Gb,
    unsigned* __restrict__ pmax, unsigned* __restrict__ brow,
    int* __restrict__ flags)
{
    __shared__ alignas(16) char lds[SGB + 1536];  // bufA@0, bufB, gbuf, pexch, sgbuf

    const int tid = threadIdx.x;
    const int b = blockIdx.x & 31, h = blockIdx.x >> 5;
    const int w = tid >> 6, l = tid & 63, lr = l & 15, q = l >> 4;
    const int g = w & 3, khalf = w >> 2;
    const int cw = g * 64 + khalf * 32;     // wave's epilogue 32-col slab

    // ---- W fragments: 4 tiles x 8 ksteps of this wave's K-half, pinned ----
    const _Float16* wtb0 = WT + (size_t)(64 * g + lr) * 512 + khalf * 256 + q * 8;
    const _Float16* wtb1 = WT + (size_t)(64 * g + 16 + lr) * 512 + khalf * 256 + q * 8;
    const _Float16* wtb2 = WT + (size_t)(64 * g + 32 + lr) * 512 + khalf * 256 + q * 8;
    const _Float16* wtb3 = WT + (size_t)(64 * g + 48 + lr) * 512 + khalf * 256 + q * 8;
#define LDW1(T, i) half8 W##T##_##i = *(const half8*)(wtb##T + i * 32); PIN(W##T##_##i)
#define LDWT(T) LDW1(T,0) LDW1(T,1) LDW1(T,2) LDW1(T,3) LDW1(T,4) LDW1(T,5) LDW1(T,6) LDW1(T,7)
    LDWT(0) LDWT(1) LDWT(2) LDWT(3)
#undef LDWT
#undef LDW1
    // gate frags: global ksteps 8*khalf + {2g, 2g+1} (union over waves = all 16)
    const _Float16* wpg = WT + (size_t)(256 + lr) * 512 + q * 8;
    const half8 WG0 = *(const half8*)(wpg + (8 * khalf + 2 * g) * 32);
    const half8 WG1 = *(const half8*)(wpg + (8 * khalf + 2 * g + 1) * 32);

    const float wb0 = Wb[cw + lr], wb1 = Wb[cw + 16 + lr];
    const float gbi0 = Gb[0], gbi1 = Gb[1], gbi2 = Gb[2];

    // ---- precomputed LDS addresses ----
#define RDA(i) const int rd##i = SWZ(lr * 512 + (8 * khalf + i) * 64 + q * 16);
    RDA(0) RDA(1) RDA(2) RDA(3) RDA(4) RDA(5) RDA(6) RDA(7)
#undef RDA
    int wo[2][4];
    #pragma unroll
    for (int nt = 0; nt < 2; ++nt)
        #pragma unroll
        for (int r = 0; r < 4; ++r)
            wo[nt][r] = SWZ((q * 4 + r) * 512 + (cw + nt * 16 + lr) * 2);
    const int impA = 8192 + l * 8;               // row 16 (identity swizzle)
    const int bnd0 = 8192 + (cw + lr) * 2;       // boundary u16 (identity swizzle)
    const int bnd1 = 8192 + (cw + 16 + lr) * 2;
    const int gwo = GBUF + (w * 16 + lr) * 16;   // gate partial slot
    const int sgw = SGB + w * 192;               // this wave's sgbuf slice
#define PSLOT(T) (PEX + (((g * 4 + (T)) * 64 + l) * 16))

    int* flagP = &flags[(b * 8 + h) * 16];       // 8 per-wave words [0..7]
    int* flagN = &flags[(b * 8 + h + 1) * 16];
    int* ackP  = &flags[(256 + b * 8 + h) * 16];
    int* ackC  = &flags[(256 + b * 8 + h - 1) * 16];
    const int slotbase = 127 * h - 8 * h * (h - 1);

    // ---- stage rows 16h..16h+16 (clamped) into BOTH buffers ----
    for (int ch = tid; ch < 17 * 32; ch += NTHR) {
        int row = ch >> 5, kc = ch & 31;
        int grow = 16 * h + row; if (grow > 127) grow = 127;
        const float* xp = x + ((size_t)b * L_ + grow) * D_ + kc * 8;
        half8 v;
        #pragma unroll
        for (int j = 0; j < 8; ++j) v[j] = (_Float16)xp[j];
        int off = SWZ(row * 512 + kc * 16);
        *(half8*)(lds + off) = v;
        *(half8*)(lds + BUFB + off) = v;
    }
    __syncthreads();

    // ---- init lv/rv carries from staged state (rows q*4..q*4+3, 2 cols) ----
    float cv0[4], cv1[4];
    #pragma unroll
    for (int i = 0; i < 4; ++i) {
        cv0[i] = (float)*(const _Float16*)(lds + SWZ((q * 4 + i) * 512 + (cw + lr) * 2));
        cv1[i] = (float)*(const _Float16*)(lds + SWZ((q * 4 + i) * 512 + (cw + 16 + lr) * 2));
    }

    int rb = 0;   // src base toggle; dst = rb ^ BUFB

    for (int t = 0; t < 127; ++t) {
        const int m = 127 - t - 16 * h;
        if (m <= 0) break;
        const int mm = (m > 16) ? 16 : m;
        const bool doExpN = (h >= 1) && (126 - t >= 16 * h);
        const bool doImpT = (h < 7) && (t <= 110 - 16 * h);
        const int rw = rb ^ BUFB;

        // ---- export-slot ack gate (ring depth 4), per wave, lane 0 ----
        if (doExpN && t >= 3 && l == 0) {
            while (__hip_atomic_load(ackC, __ATOMIC_RELAXED, __HIP_MEMORY_SCOPE_AGENT) < t - 3)
                __builtin_amdgcn_s_sleep(1);
        }

        // ---- MFMA: 4-tile partials over this wave's K-half + gate split-K ----
        f32x4 p0 = {}, p1 = {}, p2 = {}, p3 = {}, ag = {};
#define STEP(i) { \
            half8 av = *(const half8*)(lds + (rd##i ^ rb)); \
            p0 = MFMA16(av, W0_##i, p0, 0, 0, 0); \
            p1 = MFMA16(av, W1_##i, p1, 0, 0, 0); \
            p2 = MFMA16(av, W2_##i, p2, 0, 0, 0); \
            p3 = MFMA16(av, W3_##i, p3, 0, 0, 0); \
            if ((i >> 1) == g) \
                ag = MFMA16((i & 1) ? WG1 : WG0, av, ag, 0, 0, 0); }
        STEP(0) STEP(1) STEP(2) STEP(3) STEP(4) STEP(5) STEP(6) STEP(7)
#undef STEP

        // ---- write partner's 2 tiles + gate partial -> LDS ----
        if (khalf == 0) {
            *(f32x4*)(lds + PSLOT(2)) = p2;
            *(f32x4*)(lds + PSLOT(3)) = p3;
        } else {
            *(f32x4*)(lds + PSLOT(0)) = p0;
            *(f32x4*)(lds + PSLOT(1)) = p1;
        }
        if (l < 16) *(f32x4*)(lds + gwo) = ag;

        LDS_BARRIER();   // MID: partials + gate partials visible (LDS-only)

        // ---- combine own-tile partials ----
        f32x4 a0, a1;
        if (khalf == 0) {
            a0 = p0 + *(const f32x4*)(lds + PSLOT(0));
            a1 = p1 + *(const f32x4*)(lds + PSLOT(1));
        } else {
            a0 = p2 + *(const f32x4*)(lds + PSLOT(2));
            a1 = p3 + *(const f32x4*)(lds + PSLOT(3));
        }

        // ---- deterministic gate sum + in-lane softmax -> sgbuf (lanes 0..15) ----
        if (l < 16) {
            float s0g = gbi0, s1g = gbi1, s2g = gbi2;
            #pragma unroll
            for (int w8 = 0; w8 < 8; ++w8) {
                f32x4 v = *(const f32x4*)(lds + GBUF + (w8 * 16 + l) * 16);
                s0g += v[0]; s1g += v[1]; s2g += v[2];
            }
            float mg = fmaxf(fmaxf(s0g, s1g), s2g);
            float ee0 = __builtin_amdgcn_exp2f((s0g - mg) * LOG2E);
            float ee1 = __builtin_amdgcn_exp2f((s1g - mg) * LOG2E);
            float ee2 = __builtin_amdgcn_exp2f((s2g - mg) * LOG2E);
            float inv = __builtin_amdgcn_rcpf(ee0 + ee1 + ee2);
            float* sp = (float*)(lds + sgw + l * 12);
            sp[0] = ee0 * inv; sp[1] = ee1 * inv; sp[2] = ee2 * inv;
        }
        // within-wave ordering: sgbuf writes complete before broadcast reads
        asm volatile("s_waitcnt lgkmcnt(0)" ::: "memory");
        __builtin_amdgcn_sched_barrier(0);
        // broadcast read: rows q*4..q*4+3, 3 gates each (48B, same addr per group)
        f32x4 v0 = *(const f32x4*)(lds + sgw + q * 48);
        f32x4 v1 = *(const f32x4*)(lds + sgw + q * 48 + 16);
        f32x4 v2 = *(const f32x4*)(lds + sgw + q * 48 + 32);
        float g0a[4] = { v0[0], v0[3], v1[2], v2[1] };
        float g1a[4] = { v0[1], v1[0], v1[3], v2[2] };
        float g2a[4] = { v0[2], v1[1], v2[0], v2[3] };

        // ---- boundary rv (row 16, fp16) + next-q-group row-0 carry (fp32) ----
        float b0 = (float)*(const _Float16*)(lds + (bnd0 ^ rb));
        float b1 = (float)*(const _Float16*)(lds + (bnd1 ^ rb));
        float s0 = __shfl(cv0[0], (l + 16) & 63, 64);
        float s1 = __shfl(cv1[0], (l + 16) & 63, 64);

        // ---- epilogue ----
        float cm0 = -3.4e38f, cm1 = -3.4e38f;
        #pragma unroll
        for (int r = 0; r < 4; ++r) {
            const int row = q * 4 + r;
            float g0f = g0a[r];
            float g1f = g1a[r];
            float g2f = g2a[r];
            if (row < mm) {
                #define EPI(NT, ACC, CV, SHV, BV, WBV, CMV) {                                \
                    float pre = ACC[r] + WBV;                                                \
                    float exx = __builtin_amdgcn_exp2f(pre * (2.f * LOG2E));                 \
                    float ce = 1.f - 2.f * __builtin_amdgcn_rcpf(exx + 1.f);                 \
                    float lv = CV[r];                                                        \
                    float rv = (r < 3) ? CV[(r < 3) ? r + 1 : 0] : (q < 3 ? SHV : BV);       \
                    float nx = g0f * lv + g1f * ce + g2f * rv;                               \
                    CMV = fmaxf(CMV, nx);                                                    \
                    _Float16 nh = (_Float16)nx;                                              \
                    CV[r] = nx;   /* FP32 carry: no per-level rounding */                    \
                    int pdi = __builtin_amdgcn_update_dpp(                                   \
                        0, __builtin_bit_cast(int, nx), 0xB1, 0xF, 0xF, true);               \
                    float pnx = __builtin_bit_cast(float, pdi);                              \
                    unsigned pk = (unsigned)__builtin_bit_cast(unsigned short, nh)           \
                        | ((unsigned)__builtin_bit_cast(unsigned short, (_Float16)pnx) << 16);\
                    if (!(lr & 1)) {                                                         \
                        *(unsigned*)(lds + (wo[NT][r] ^ rw)) = pk;                           \
                        if (r == 0 && q == 0 && doExpN) {                                    \
                            unsigned* ep = brow +                                            \
                                (((size_t)((t + 1) & 3) * 32 + b) * 8 + h) * 128             \
                                + (cw >> 1) + NT * 8 + (lr >> 1);                            \
                            __hip_atomic_store(ep, pk, __ATOMIC_RELAXED,                     \
                                               __HIP_MEMORY_SCOPE_AGENT);                    \
                        }                                                                    \
                    }                                                                        \
                }
                EPI(0, a0, cv0, s0, b0, wb0, cm0)
                EPI(1, a1, cv1, s1, b1, wb1, cm1)
                #undef EPI
            }
        }

        // ---- EARLY FLAG: per-wave, after this wave's export stores drained ----
        if (doExpN) {
            asm volatile("s_waitcnt vmcnt(0)" ::: "memory");
            if (l == 0)
                __hip_atomic_store(&flagP[w], t + 1,
                                   __ATOMIC_RELAXED, __HIP_MEMORY_SCOPE_AGENT);
        }

        // ---- wave 0: poll neighbor's 8 early flags, ISSUE import load ----
        unsigned long long iv = 0;
        if (w == 0 && doImpT) {
            if (l < 8) {
                while (__hip_atomic_load(&flagN[l], __ATOMIC_RELAXED,
                                         __HIP_MEMORY_SCOPE_AGENT) < t + 1)
                    __builtin_amdgcn_s_sleep(1);
            }
            const unsigned long long* bp = (const unsigned long long*)brow
                + (((size_t)((t + 1) & 3) * 32 + b) * 8 + (h + 1)) * 64 + l;
            iv = __hip_atomic_load(bp, __ATOMIC_RELAXED, __HIP_MEMORY_SCOPE_AGENT);
        }

        // ---- col-max -> private pmax slot (overlaps the import load) ----
        cm0 = fmaxf(cm0, __shfl_xor(cm0, 16, 64));
        cm0 = fmaxf(cm0, __shfl_xor(cm0, 32, 64));
        cm1 = fmaxf(cm1, __shfl_xor(cm1, 16, 64));
        cm1 = fmaxf(cm1, __shfl_xor(cm1, 32, 64));
        if (l < 16) {
            unsigned ph = (unsigned)__builtin_bit_cast(unsigned short, (_Float16)cm0)
                        | ((unsigned)__builtin_bit_cast(unsigned short, (_Float16)cm1) << 16);
            pmax[((size_t)b * PS_SLOTS + slotbase + t) * 128 + w * 16 + l] = ph;
        }

        // ---- wave 0: land import into DST row 16, ack ----
        if (w == 0 && doImpT) {
            *(unsigned long long*)(lds + (impA ^ rw)) = iv;
            if (l == 0)
                __hip_atomic_store(ackP, t + 1, __ATOMIC_RELAXED, __HIP_MEMORY_SCOPE_AGENT);
        }

        LDS_BARRIER();   // END: dst rows + import visible (LDS-only)
        rb ^= BUFB;
    }
}

extern "C" void kernel_launch(void* const* d_in, const int* in_sizes, int n_in,
                              void* d_out, int out_size, void* d_ws, size_t ws_size,
                              hipStream_t stream) {
    const float* x  = (const float*)d_in[0];
    const float* Wl = (const float*)d_in[1];
    const float* Wr = (const float*)d_in[2];
    const float* Wb = (const float*)d_in[3];
    const float* Gl = (const float*)d_in[4];
    const float* Gr = (const float*)d_in[5];
    const float* Gb = (const float*)d_in[6];
    float* out = (float*)d_out;
    char* ws = (char*)d_ws;

    _Float16* WT = (_Float16*)ws;                         // 278,528 B
    unsigned* brow = (unsigned*)(ws + 278528);            // 524,288 B (ring 4)
    int* flags = (int*)(ws + 802816);                     // 32,768 B
    unsigned* pmax = (unsigned*)(ws + 835584);            // 9,306,112 B

    prep_wt<<<272, 256, 0, stream>>>(Wl, Wr, Gl, Gr, WT);
    init_misc<<<B_, 256, 0, stream>>>(x, out, flags);

    void* args[] = { (void*)&x, (void*)&WT, (void*)&Wb, (void*)&Gb,
                     (void*)&pmax, (void*)&brow, (void*)&flags };
    hipLaunchCooperativeKernel((const void*)grcnn_main, dim3(B_ * 8), dim3(NTHR),
                               args, 0, stream);

    decode_out<<<1024, 256, 0, stream>>>(pmax, out);
}

// Round 18
// 412.147 us; speedup vs baseline: 1.0915x; 1.0915x over previous
//
#include <hip/hip_runtime.h>

// GrCNN: B=32, L=128, D=256, 127 sequential levels.
// Round 18: = round 17 (passed, 450us; bit-identical compute to r15) with the
// cross-block rendezvous collapsed to ONE L3 round trip:
//  - TAG-IN-DATA GRANULES: boundary-row exchange = 128 u64 granules/row, each
//    {pk 4B data | (t+1)<<32 tag}, written with relaxed agent atomic stores
//    straight from the epilogue. The data store IS the signal: no producer
//    vmcnt drain, no flag store, no flag poll. Consumer lanes poll their own
//    2 granules; first load with tag==t+1 is the data.
//  - ring depth 2 (same 512KB brow); reuse gate ackC >= t-1 (1.5 levels
//    slack, acyclic). brow ZEROED in init_misc each launch (graph-replay
//    staleness: previous replay's tags would alias t+1).
// K-split pairing, fp32 carries, pinned W (AGPR-resident), sgbuf gate
// broadcast, LDS-only barriers, pmax+decode identical to r17.

#define B_ 32
#define L_ 128
#define D_ 256
#define NTHR 512
#define BUFB 16384
#define GBUF 25088            // gbuf: [w][16] f32x4 = 2048 B
#define PEX  27136            // pexch: [g][tile][lane] f32x4 = 16384 B
#define SGB  43520            // sgbuf: [w][16][3] float = 1536 B
#define LOG2E 1.4426950408889634f
#define PS_SLOTS 568          // sum_{h=0}^{7} (127-16h)
#define BROW_U64 65536        // 2 slots * 32 b * 8 h * 128 granules

typedef _Float16 half8 __attribute__((ext_vector_type(8)));
typedef float f32x4 __attribute__((ext_vector_type(4)));
typedef unsigned u32x4 __attribute__((ext_vector_type(4)));

#define SWZ(o)  ((o) ^ ((((o) >> 9) & 7) << 4))
#define MFMA16 __builtin_amdgcn_mfma_f32_16x16x32_f16
// LDS-only barrier: no vmcnt drain (granule stores are self-signaling;
// pmax has no intra-kernel consumer)
#define LDS_BARRIER() asm volatile("s_waitcnt lgkmcnt(0)\n\ts_barrier" ::: "memory")

// 32-bit-component register pin (r13-verified: stays resident, no remat)
#define PIN(H) { \
    u32x4 t_ = __builtin_bit_cast(u32x4, H); \
    unsigned p0_ = t_[0], p1_ = t_[1], p2_ = t_[2], p3_ = t_[3]; \
    asm volatile("" : "+v"(p0_), "+v"(p1_), "+v"(p2_), "+v"(p3_)); \
    t_[0] = p0_; t_[1] = p1_; t_[2] = p2_; t_[3] = p3_; \
    H = __builtin_bit_cast(half8, t_); }

// ---- WT[272][512] fp16: col j -> 512 k (k<256: Wl/Gl row k, else Wr/Gr) ----
__global__ void prep_wt(const float* __restrict__ Wl, const float* __restrict__ Wr,
                        const float* __restrict__ Gl, const float* __restrict__ Gr,
                        _Float16* __restrict__ WT) {
    int j = blockIdx.x;
    for (int k = threadIdx.x; k < 512; k += 256) {
        float v = 0.f;
        if (j < 256) v = (k < 256) ? Wl[k * 256 + j] : Wr[(k - 256) * 256 + j];
        else { int jj = j - 256; if (jj < 3) v = (k < 256) ? Gl[k * 3 + jj] : Gr[(k - 256) * 3 + jj]; }
        WT[(size_t)j * 512 + k] = (_Float16)v;
    }
}

// ---- init: zero acks, ZERO brow (replay staleness), level-0 col max ----
__global__ void init_misc(const float* __restrict__ x, float* __restrict__ out,
                          int* __restrict__ flags, unsigned long long* __restrict__ brow) {
    int b = blockIdx.x, c = threadIdx.x;
    if (b == 0) for (int i = c; i < 2 * 256 * 16; i += 256) flags[i] = 0;
    for (int i = b * 256 + c; i < BROW_U64; i += 32 * 256) brow[i] = 0ull;
    float m = -3.4e38f;
    for (int row = 0; row < L_; ++row)
        m = fmaxf(m, x[((size_t)b * L_ + row) * D_ + c]);
    out[(size_t)b * L_ * D_ + c] = m;
}

// ---- decode: pmax partials -> out levels 1..127 (col map for K-split waves) ----
__global__ void decode_out(const unsigned* __restrict__ pmax, float* __restrict__ out) {
    for (size_t i = (size_t)blockIdx.x * 256 + threadIdx.x; i < (size_t)32 * 127 * 256;
         i += (size_t)gridDim.x * 256) {
        int c = (int)(i & 255);
        int k = (int)((i >> 8) % 127) + 1;
        int b = (int)(i / (127 * 256));
        int hcnt = (143 - k) >> 4;              // ceil((128-k)/16)
        // c = 64g + 32khalf + 16NT + lr; w = 4khalf+g; dw = w*16+lr
        int dw = ((c >> 5) & 1) * 64 + ((c >> 6) & 3) * 16 + (c & 15);
        int hi = (c >> 4) & 1;                  // NT
        float mx = -3.4e38f;
        for (int h = 0; h < hcnt; ++h) {
            int slot = 127 * h - 8 * h * (h - 1) + (k - 1);
            unsigned u = pmax[((size_t)b * PS_SLOTS + slot) * 128 + dw];
            unsigned short us = hi ? (unsigned short)(u >> 16) : (unsigned short)(u & 0xffff);
            float v = (float)__builtin_bit_cast(_Float16, us);
            mx = fmaxf(mx, v);
        }
        out[((size_t)b * 128 + k) * 256 + c] = mx;
    }
}

__global__ __launch_bounds__(NTHR, 2) void grcnn_main(
    const float* __restrict__ x, const _Float16* __restrict__ WT,
    const float* __restrict__ Wb, const float* __restrict__ Gb,
    unsigned* __restrict__ pmax, unsigned long long* __restrict__ brow,
    int* __restrict__ flags)
{
    __shared__ alignas(16) char lds[SGB + 1536];  // bufA@0, bufB, gbuf, pexch, sgbuf

    const int tid = threadIdx.x;
    const int b = blockIdx.x & 31, h = blockIdx.x >> 5;
    const int w = tid >> 6, l = tid & 63, lr = l & 15, q = l >> 4;
    const int g = w & 3, khalf = w >> 2;
    const int cw = g * 64 + khalf * 32;     // wave's epilogue 32-col slab

    // ---- W fragments: 4 tiles x 8 ksteps of this wave's K-half, pinned ----
    const _Float16* wtb0 = WT + (size_t)(64 * g + lr) * 512 + khalf * 256 + q * 8;
    const _Float16* wtb1 = WT + (size_t)(64 * g + 16 + lr) * 512 + khalf * 256 + q * 8;
    const _Float16* wtb2 = WT + (size_t)(64 * g + 32 + lr) * 512 + khalf * 256 + q * 8;
    const _Float16* wtb3 = WT + (size_t)(64 * g + 48 + lr) * 512 + khalf * 256 + q * 8;
#define LDW1(T, i) half8 W##T##_##i = *(const half8*)(wtb##T + i * 32); PIN(W##T##_##i)
#define LDWT(T) LDW1(T,0) LDW1(T,1) LDW1(T,2) LDW1(T,3) LDW1(T,4) LDW1(T,5) LDW1(T,6) LDW1(T,7)
    LDWT(0) LDWT(1) LDWT(2) LDWT(3)
#undef LDWT
#undef LDW1
    // gate frags: global ksteps 8*khalf + {2g, 2g+1} (union over waves = all 16)
    const _Float16* wpg = WT + (size_t)(256 + lr) * 512 + q * 8;
    const half8 WG0 = *(const half8*)(wpg + (8 * khalf + 2 * g) * 32);
    const half8 WG1 = *(const half8*)(wpg + (8 * khalf + 2 * g + 1) * 32);

    const float wb0 = Wb[cw + lr], wb1 = Wb[cw + 16 + lr];
    const float gbi0 = Gb[0], gbi1 = Gb[1], gbi2 = Gb[2];

    // ---- precomputed LDS addresses ----
#define RDA(i) const int rd##i = SWZ(lr * 512 + (8 * khalf + i) * 64 + q * 16);
    RDA(0) RDA(1) RDA(2) RDA(3) RDA(4) RDA(5) RDA(6) RDA(7)
#undef RDA
    int wo[2][4];
    #pragma unroll
    for (int nt = 0; nt < 2; ++nt)
        #pragma unroll
        for (int r = 0; r < 4; ++r)
            wo[nt][r] = SWZ((q * 4 + r) * 512 + (cw + nt * 16 + lr) * 2);
    const int impA = 8192 + l * 8;               // row 16 (identity swizzle)
    const int bnd0 = 8192 + (cw + lr) * 2;       // boundary u16 (identity swizzle)
    const int bnd1 = 8192 + (cw + 16 + lr) * 2;
    const int gwo = GBUF + (w * 16 + lr) * 16;   // gate partial slot
    const int sgw = SGB + w * 192;               // this wave's sgbuf slice
#define PSLOT(T) (PEX + (((g * 4 + (T)) * 64 + l) * 16))

    int* ackP  = &flags[(256 + b * 8 + h) * 16];
    int* ackC  = &flags[(256 + b * 8 + h - 1) * 16];
    const int slotbase = 127 * h - 8 * h * (h - 1);

    // ---- stage rows 16h..16h+16 (clamped) into BOTH buffers ----
    for (int ch = tid; ch < 17 * 32; ch += NTHR) {
        int row = ch >> 5, kc = ch & 31;
        int grow = 16 * h + row; if (grow > 127) grow = 127;
        const float* xp = x + ((size_t)b * L_ + grow) * D_ + kc * 8;
        half8 v;
        #pragma unroll
        for (int j = 0; j < 8; ++j) v[j] = (_Float16)xp[j];
        int off = SWZ(row * 512 + kc * 16);
        *(half8*)(lds + off) = v;
        *(half8*)(lds + BUFB + off) = v;
    }
    __syncthreads();

    // ---- init lv/rv carries from staged state (rows q*4..q*4+3, 2 cols) ----
    float cv0[4], cv1[4];
    #pragma unroll
    for (int i = 0; i < 4; ++i) {
        cv0[i] = (float)*(const _Float16*)(lds + SWZ((q * 4 + i) * 512 + (cw + lr) * 2));
        cv1[i] = (float)*(const _Float16*)(lds + SWZ((q * 4 + i) * 512 + (cw + 16 + lr) * 2));
    }

    int rb = 0;   // src base toggle; dst = rb ^ BUFB

    for (int t = 0; t < 127; ++t) {
        const int m = 127 - t - 16 * h;
        if (m <= 0) break;
        const int mm = (m > 16) ? 16 : m;
        const bool doExpN = (h >= 1) && (126 - t >= 16 * h);
        const bool doImpT = (h < 7) && (t <= 110 - 16 * h);
        const int rw = rb ^ BUFB;

        // ---- export-slot reuse gate (ring depth 2), per wave, lane 0 ----
        if (doExpN && t >= 1 && l == 0) {
            while (__hip_atomic_load(ackC, __ATOMIC_RELAXED, __HIP_MEMORY_SCOPE_AGENT) < t - 1)
                __builtin_amdgcn_s_sleep(1);
        }

        // ---- MFMA: 4-tile partials over this wave's K-half + gate split-K ----
        f32x4 p0 = {}, p1 = {}, p2 = {}, p3 = {}, ag = {};
#define STEP(i) { \
            half8 av = *(const half8*)(lds + (rd##i ^ rb)); \
            p0 = MFMA16(av, W0_##i, p0, 0, 0, 0); \
            p1 = MFMA16(av, W1_##i, p1, 0, 0, 0); \
            p2 = MFMA16(av, W2_##i, p2, 0, 0, 0); \
            p3 = MFMA16(av, W3_##i, p3, 0, 0, 0); \
            if ((i >> 1) == g) \
                ag = MFMA16((i & 1) ? WG1 : WG0, av, ag, 0, 0, 0); }
        STEP(0) STEP(1) STEP(2) STEP(3) STEP(4) STEP(5) STEP(6) STEP(7)
#undef STEP

        // ---- write partner's 2 tiles + gate partial -> LDS ----
        if (khalf == 0) {
            *(f32x4*)(lds + PSLOT(2)) = p2;
            *(f32x4*)(lds + PSLOT(3)) = p3;
        } else {
            *(f32x4*)(lds + PSLOT(0)) = p0;
            *(f32x4*)(lds + PSLOT(1)) = p1;
        }
        if (l < 16) *(f32x4*)(lds + gwo) = ag;

        LDS_BARRIER();   // MID: partials + gate partials visible (LDS-only)

        // ---- combine own-tile partials ----
        f32x4 a0, a1;
        if (khalf == 0) {
            a0 = p0 + *(const f32x4*)(lds + PSLOT(0));
            a1 = p1 + *(const f32x4*)(lds + PSLOT(1));
        } else {
            a0 = p2 + *(const f32x4*)(lds + PSLOT(2));
            a1 = p3 + *(const f32x4*)(lds + PSLOT(3));
        }

        // ---- deterministic gate sum + in-lane softmax -> sgbuf (lanes 0..15) ----
        if (l < 16) {
            float s0g = gbi0, s1g = gbi1, s2g = gbi2;
            #pragma unroll
            for (int w8 = 0; w8 < 8; ++w8) {
                f32x4 v = *(const f32x4*)(lds + GBUF + (w8 * 16 + l) * 16);
                s0g += v[0]; s1g += v[1]; s2g += v[2];
            }
            float mg = fmaxf(fmaxf(s0g, s1g), s2g);
            float ee0 = __builtin_amdgcn_exp2f((s0g - mg) * LOG2E);
            float ee1 = __builtin_amdgcn_exp2f((s1g - mg) * LOG2E);
            float ee2 = __builtin_amdgcn_exp2f((s2g - mg) * LOG2E);
            float inv = __builtin_amdgcn_rcpf(ee0 + ee1 + ee2);
            float* sp = (float*)(lds + sgw + l * 12);
            sp[0] = ee0 * inv; sp[1] = ee1 * inv; sp[2] = ee2 * inv;
        }
        // within-wave ordering: sgbuf writes complete before broadcast reads
        asm volatile("s_waitcnt lgkmcnt(0)" ::: "memory");
        __builtin_amdgcn_sched_barrier(0);
        // broadcast read: rows q*4..q*4+3, 3 gates each (48B, same addr per group)
        f32x4 v0 = *(const f32x4*)(lds + sgw + q * 48);
        f32x4 v1 = *(const f32x4*)(lds + sgw + q * 48 + 16);
        f32x4 v2 = *(const f32x4*)(lds + sgw + q * 48 + 32);
        float g0a[4] = { v0[0], v0[3], v1[2], v2[1] };
        float g1a[4] = { v0[1], v1[0], v1[3], v2[2] };
        float g2a[4] = { v0[2], v1[1], v2[0], v2[3] };

        // ---- boundary rv (row 16, fp16) + next-q-group row-0 carry (fp32) ----
        float b0 = (float)*(const _Float16*)(lds + (bnd0 ^ rb));
        float b1 = (float)*(const _Float16*)(lds + (bnd1 ^ rb));
        float s0 = __shfl(cv0[0], (l + 16) & 63, 64);
        float s1 = __shfl(cv1[0], (l + 16) & 63, 64);

        // ---- epilogue (exports = self-signaling tagged u64 granules) ----
        const unsigned long long tagv = (unsigned long long)(t + 1) << 32;
        float cm0 = -3.4e38f, cm1 = -3.4e38f;
        #pragma unroll
        for (int r = 0; r < 4; ++r) {
            const int row = q * 4 + r;
            float g0f = g0a[r];
            float g1f = g1a[r];
            float g2f = g2a[r];
            if (row < mm) {
                #define EPI(NT, ACC, CV, SHV, BV, WBV, CMV) {                                \
                    float pre = ACC[r] + WBV;                                                \
                    float exx = __builtin_amdgcn_exp2f(pre * (2.f * LOG2E));                 \
                    float ce = 1.f - 2.f * __builtin_amdgcn_rcpf(exx + 1.f);                 \
                    float lv = CV[r];                                                        \
                    float rv = (r < 3) ? CV[(r < 3) ? r + 1 : 0] : (q < 3 ? SHV : BV);       \
                    float nx = g0f * lv + g1f * ce + g2f * rv;                               \
                    CMV = fmaxf(CMV, nx);                                                    \
                    _Float16 nh = (_Float16)nx;                                              \
                    CV[r] = nx;   /* FP32 carry: no per-level rounding */                    \
                    int pdi = __builtin_amdgcn_update_dpp(                                   \
                        0, __builtin_bit_cast(int, nx), 0xB1, 0xF, 0xF, true);               \
                    float pnx = __builtin_bit_cast(float, pdi);                              \
                    unsigned pk = (unsigned)__builtin_bit_cast(unsigned short, nh)           \
                        | ((unsigned)__builtin_bit_cast(unsigned short, (_Float16)pnx) << 16);\
                    if (!(lr & 1)) {                                                         \
                        *(unsigned*)(lds + (wo[NT][r] ^ rw)) = pk;                           \
                        if (r == 0 && q == 0 && doExpN) {                                    \
                            unsigned long long* ep = brow +                                  \
                                (((size_t)((t + 1) & 1) * 32 + b) * 8 + h) * 128             \
                                + (cw >> 1) + NT * 8 + (lr >> 1);                            \
                            __hip_atomic_store(ep, (unsigned long long)pk | tagv,            \
                                               __ATOMIC_RELAXED, __HIP_MEMORY_SCOPE_AGENT);  \
                        }                                                                    \
                    }                                                                        \
                }
                EPI(0, a0, cv0, s0, b0, wb0, cm0)
                EPI(1, a1, cv1, s1, b1, wb1, cm1)
                #undef EPI
            }
        }

        // ---- wave 0: first-try granule loads (overlap with cm-reduce) ----
        unsigned long long g0v = 0, g1v = 0;
        const unsigned long long* bp = nullptr;
        if (w == 0 && doImpT) {
            bp = brow + (((size_t)((t + 1) & 1) * 32 + b) * 8 + (h + 1)) * 128 + 2 * l;
            g0v = __hip_atomic_load(bp,     __ATOMIC_RELAXED, __HIP_MEMORY_SCOPE_AGENT);
            g1v = __hip_atomic_load(bp + 1, __ATOMIC_RELAXED, __HIP_MEMORY_SCOPE_AGENT);
        }

        // ---- col-max -> private pmax slot (overlaps the granule loads) ----
        cm0 = fmaxf(cm0, __shfl_xor(cm0, 16, 64));
        cm0 = fmaxf(cm0, __shfl_xor(cm0, 32, 64));
        cm1 = fmaxf(cm1, __shfl_xor(cm1, 16, 64));
        cm1 = fmaxf(cm1, __shfl_xor(cm1, 32, 64));
        if (l < 16) {
            unsigned ph = (unsigned)__builtin_bit_cast(unsigned short, (_Float16)cm0)
                        | ((unsigned)__builtin_bit_cast(unsigned short, (_Float16)cm1) << 16);
            pmax[((size_t)b * PS_SLOTS + slotbase + t) * 128 + w * 16 + l] = ph;
        }

        // ---- wave 0: poll tags, land import into DST row 16, ack ----
        if (w == 0 && doImpT) {
            const unsigned tag = (unsigned)(t + 1);
            while ((unsigned)(g0v >> 32) != tag) {
                __builtin_amdgcn_s_sleep(1);
                g0v = __hip_atomic_load(bp, __ATOMIC_RELAXED, __HIP_MEMORY_SCOPE_AGENT);
            }
            while ((unsigned)(g1v >> 32) != tag) {
                __builtin_amdgcn_s_sleep(1);
                g1v = __hip_atomic_load(bp + 1, __ATOMIC_RELAXED, __HIP_MEMORY_SCOPE_AGENT);
            }
            unsigned long long data = (g0v & 0xffffffffull) | (g1v << 32);
            *(unsigned long long*)(lds + (impA ^ rw)) = data;
            if (l == 0)
                __hip_atomic_store(ackP, t + 1, __ATOMIC_RELAXED, __HIP_MEMORY_SCOPE_AGENT);
        }

        LDS_BARRIER();   // END: dst rows + import visible (LDS-only)
        rb ^= BUFB;
    }
}

extern "C" void kernel_launch(void* const* d_in, const int* in_sizes, int n_in,
                              void* d_out, int out_size, void* d_ws, size_t ws_size,
                              hipStream_t stream) {
    const float* x  = (const float*)d_in[0];
    const float* Wl = (const float*)d_in[1];
    const float* Wr = (const float*)d_in[2];
    const float* Wb = (const float*)d_in[3];
    const float* Gl = (const float*)d_in[4];
    const float* Gr = (const float*)d_in[5];
    const float* Gb = (const float*)d_in[6];
    float* out = (float*)d_out;
    char* ws = (char*)d_ws;

    _Float16* WT = (_Float16*)ws;                               // 278,528 B
    unsigned long long* brow = (unsigned long long*)(ws + 278528); // 524,288 B (ring 2, tagged)
    int* flags = (int*)(ws + 802816);                           // 32,768 B (acks)
    unsigned* pmax = (unsigned*)(ws + 835584);                  // 9,306,112 B

    prep_wt<<<272, 256, 0, stream>>>(Wl, Wr, Gl, Gr, WT);
    init_misc<<<B_, 256, 0, stream>>>(x, out, flags, brow);

    void* args[] = { (void*)&x, (void*)&WT, (void*)&Wb, (void*)&Gb,
                     (void*)&pmax, (void*)&brow, (void*)&flags };
    hipLaunchCooperativeKernel((const void*)grcnn_main, dim3(B_ * 8), dim3(NTHR),
                               args, 0, stream);

    decode_out<<<1024, 256, 0, stream>>>(pmax, out);
}

// Round 19
// 386.130 us; speedup vs baseline: 1.1650x; 1.0674x over previous
//
#include <hip/hip_runtime.h>

// GrCNN: B=32, L=128, D=256, 127 sequential levels.
// Round 19: = round 18 (passed, 412us; main 360us) + the level-0 col-max
// folded INTO grcnn_main (computed from the cv carries the staging already
// holds, stored to pmax0[b][h][128], decoded by decode_out k==0). init_misc
// shrinks to flags+brow zeroing (~2us, was ~30-40us scanning 4MB of x with
// 32 blocks). Level-0 max uses fp16-rounded x: error <= 2^-11 (~0.002),
// inside margin. Per-level numerics bit-identical to r18:
//  - tag-in-data u64 granule rendezvous (1 L3 round trip, ring 2, ack gate)
//  - K-split pairing, fp32 carries, pinned W (AGPR-resident)
//  - sgbuf gate broadcast, LDS-only barriers, pmax+decode partial-max scheme

#define B_ 32
#define L_ 128
#define D_ 256
#define NTHR 512
#define BUFB 16384
#define GBUF 25088            // gbuf: [w][16] f32x4 = 2048 B
#define PEX  27136            // pexch: [g][tile][lane] f32x4 = 16384 B
#define SGB  43520            // sgbuf: [w][16][3] float = 1536 B
#define LOG2E 1.4426950408889634f
#define PS_SLOTS 568          // sum_{h=0}^{7} (127-16h)
#define BROW_U64 65536        // 2 slots * 32 b * 8 h * 128 granules

typedef _Float16 half8 __attribute__((ext_vector_type(8)));
typedef float f32x4 __attribute__((ext_vector_type(4)));
typedef unsigned u32x4 __attribute__((ext_vector_type(4)));

#define SWZ(o)  ((o) ^ ((((o) >> 9) & 7) << 4))
#define MFMA16 __builtin_amdgcn_mfma_f32_16x16x32_f16
// LDS-only barrier: no vmcnt drain (granule stores are self-signaling;
// pmax has no intra-kernel consumer)
#define LDS_BARRIER() asm volatile("s_waitcnt lgkmcnt(0)\n\ts_barrier" ::: "memory")

// 32-bit-component register pin (r13-verified: stays resident, no remat)
#define PIN(H) { \
    u32x4 t_ = __builtin_bit_cast(u32x4, H); \
    unsigned p0_ = t_[0], p1_ = t_[1], p2_ = t_[2], p3_ = t_[3]; \
    asm volatile("" : "+v"(p0_), "+v"(p1_), "+v"(p2_), "+v"(p3_)); \
    t_[0] = p0_; t_[1] = p1_; t_[2] = p2_; t_[3] = p3_; \
    H = __builtin_bit_cast(half8, t_); }

// ---- WT[272][512] fp16: col j -> 512 k (k<256: Wl/Gl row k, else Wr/Gr) ----
__global__ void prep_wt(const float* __restrict__ Wl, const float* __restrict__ Wr,
                        const float* __restrict__ Gl, const float* __restrict__ Gr,
                        _Float16* __restrict__ WT) {
    int j = blockIdx.x;
    for (int k = threadIdx.x; k < 512; k += 256) {
        float v = 0.f;
        if (j < 256) v = (k < 256) ? Wl[k * 256 + j] : Wr[(k - 256) * 256 + j];
        else { int jj = j - 256; if (jj < 3) v = (k < 256) ? Gl[k * 3 + jj] : Gr[(k - 256) * 3 + jj]; }
        WT[(size_t)j * 512 + k] = (_Float16)v;
    }
}

// ---- init: zero acks + brow only (level-0 max moved into grcnn_main) ----
__global__ void init_misc(int* __restrict__ flags, unsigned long long* __restrict__ brow) {
    int b = blockIdx.x, c = threadIdx.x;
    if (b == 0) for (int i = c; i < 2 * 256 * 16; i += 256) flags[i] = 0;
    for (int i = b * 256 + c; i < BROW_U64; i += 32 * 256) brow[i] = 0ull;
}

// ---- decode: pmax/pmax0 partials -> out levels 0..127 ----
__global__ void decode_out(const unsigned* __restrict__ pmax, float* __restrict__ out) {
    const unsigned* pmax0 = pmax + (size_t)32 * PS_SLOTS * 128;  // [b][h][128]
    for (size_t i = (size_t)blockIdx.x * 256 + threadIdx.x; i < (size_t)32 * 128 * 256;
         i += (size_t)gridDim.x * 256) {
        int c = (int)(i & 255);
        int k = (int)((i >> 8) & 127);
        int b = (int)(i / (128 * 256));
        // c = 64g + 32khalf + 16NT + lr; w = 4khalf+g; dw = w*16+lr
        int dw = ((c >> 5) & 1) * 64 + ((c >> 6) & 3) * 16 + (c & 15);
        int hi = (c >> 4) & 1;                  // NT
        float mx = -3.4e38f;
        if (k == 0) {
            #pragma unroll
            for (int h = 0; h < 8; ++h) {
                unsigned u = pmax0[((size_t)b * 8 + h) * 128 + dw];
                unsigned short us = hi ? (unsigned short)(u >> 16) : (unsigned short)(u & 0xffff);
                mx = fmaxf(mx, (float)__builtin_bit_cast(_Float16, us));
            }
        } else {
            int hcnt = (143 - k) >> 4;          // ceil((128-k)/16)
            for (int h = 0; h < hcnt; ++h) {
                int slot = 127 * h - 8 * h * (h - 1) + (k - 1);
                unsigned u = pmax[((size_t)b * PS_SLOTS + slot) * 128 + dw];
                unsigned short us = hi ? (unsigned short)(u >> 16) : (unsigned short)(u & 0xffff);
                mx = fmaxf(mx, (float)__builtin_bit_cast(_Float16, us));
            }
        }
        out[((size_t)b * 128 + k) * 256 + c] = mx;
    }
}

__global__ __launch_bounds__(NTHR, 2) void grcnn_main(
    const float* __restrict__ x, const _Float16* __restrict__ WT,
    const float* __restrict__ Wb, const float* __restrict__ Gb,
    unsigned* __restrict__ pmax, unsigned long long* __restrict__ brow,
    int* __restrict__ flags)
{
    __shared__ alignas(16) char lds[SGB + 1536];  // bufA@0, bufB, gbuf, pexch, sgbuf

    const int tid = threadIdx.x;
    const int b = blockIdx.x & 31, h = blockIdx.x >> 5;
    const int w = tid >> 6, l = tid & 63, lr = l & 15, q = l >> 4;
    const int g = w & 3, khalf = w >> 2;
    const int cw = g * 64 + khalf * 32;     // wave's epilogue 32-col slab

    // ---- W fragments: 4 tiles x 8 ksteps of this wave's K-half, pinned ----
    const _Float16* wtb0 = WT + (size_t)(64 * g + lr) * 512 + khalf * 256 + q * 8;
    const _Float16* wtb1 = WT + (size_t)(64 * g + 16 + lr) * 512 + khalf * 256 + q * 8;
    const _Float16* wtb2 = WT + (size_t)(64 * g + 32 + lr) * 512 + khalf * 256 + q * 8;
    const _Float16* wtb3 = WT + (size_t)(64 * g + 48 + lr) * 512 + khalf * 256 + q * 8;
#define LDW1(T, i) half8 W##T##_##i = *(const half8*)(wtb##T + i * 32); PIN(W##T##_##i)
#define LDWT(T) LDW1(T,0) LDW1(T,1) LDW1(T,2) LDW1(T,3) LDW1(T,4) LDW1(T,5) LDW1(T,6) LDW1(T,7)
    LDWT(0) LDWT(1) LDWT(2) LDWT(3)
#undef LDWT
#undef LDW1
    // gate frags: global ksteps 8*khalf + {2g, 2g+1} (union over waves = all 16)
    const _Float16* wpg = WT + (size_t)(256 + lr) * 512 + q * 8;
    const half8 WG0 = *(const half8*)(wpg + (8 * khalf + 2 * g) * 32);
    const half8 WG1 = *(const half8*)(wpg + (8 * khalf + 2 * g + 1) * 32);

    const float wb0 = Wb[cw + lr], wb1 = Wb[cw + 16 + lr];
    const float gbi0 = Gb[0], gbi1 = Gb[1], gbi2 = Gb[2];

    // ---- precomputed LDS addresses ----
#define RDA(i) const int rd##i = SWZ(lr * 512 + (8 * khalf + i) * 64 + q * 16);
    RDA(0) RDA(1) RDA(2) RDA(3) RDA(4) RDA(5) RDA(6) RDA(7)
#undef RDA
    int wo[2][4];
    #pragma unroll
    for (int nt = 0; nt < 2; ++nt)
        #pragma unroll
        for (int r = 0; r < 4; ++r)
            wo[nt][r] = SWZ((q * 4 + r) * 512 + (cw + nt * 16 + lr) * 2);
    const int impA = 8192 + l * 8;               // row 16 (identity swizzle)
    const int bnd0 = 8192 + (cw + lr) * 2;       // boundary u16 (identity swizzle)
    const int bnd1 = 8192 + (cw + 16 + lr) * 2;
    const int gwo = GBUF + (w * 16 + lr) * 16;   // gate partial slot
    const int sgw = SGB + w * 192;               // this wave's sgbuf slice
#define PSLOT(T) (PEX + (((g * 4 + (T)) * 64 + l) * 16))

    int* ackP  = &flags[(256 + b * 8 + h) * 16];
    int* ackC  = &flags[(256 + b * 8 + h - 1) * 16];
    const int slotbase = 127 * h - 8 * h * (h - 1);
    unsigned* pmax0 = pmax + (size_t)32 * PS_SLOTS * 128;

    // ---- stage rows 16h..16h+16 (clamped) into BOTH buffers ----
    for (int ch = tid; ch < 17 * 32; ch += NTHR) {
        int row = ch >> 5, kc = ch & 31;
        int grow = 16 * h + row; if (grow > 127) grow = 127;
        const float* xp = x + ((size_t)b * L_ + grow) * D_ + kc * 8;
        half8 v;
        #pragma unroll
        for (int j = 0; j < 8; ++j) v[j] = (_Float16)xp[j];
        int off = SWZ(row * 512 + kc * 16);
        *(half8*)(lds + off) = v;
        *(half8*)(lds + BUFB + off) = v;
    }
    __syncthreads();

    // ---- init lv/rv carries from staged state (rows q*4..q*4+3, 2 cols) ----
    float cv0[4], cv1[4];
    #pragma unroll
    for (int i = 0; i < 4; ++i) {
        cv0[i] = (float)*(const _Float16*)(lds + SWZ((q * 4 + i) * 512 + (cw + lr) * 2));
        cv1[i] = (float)*(const _Float16*)(lds + SWZ((q * 4 + i) * 512 + (cw + 16 + lr) * 2));
    }

    // ---- level-0 col-max from carries -> pmax0[b][h] (replaces init_misc scan) ----
    {
        float c0 = fmaxf(fmaxf(cv0[0], cv0[1]), fmaxf(cv0[2], cv0[3]));
        float c1 = fmaxf(fmaxf(cv1[0], cv1[1]), fmaxf(cv1[2], cv1[3]));
        c0 = fmaxf(c0, __shfl_xor(c0, 16, 64)); c0 = fmaxf(c0, __shfl_xor(c0, 32, 64));
        c1 = fmaxf(c1, __shfl_xor(c1, 16, 64)); c1 = fmaxf(c1, __shfl_xor(c1, 32, 64));
        if (l < 16) {
            unsigned ph = (unsigned)__builtin_bit_cast(unsigned short, (_Float16)c0)
                        | ((unsigned)__builtin_bit_cast(unsigned short, (_Float16)c1) << 16);
            pmax0[((size_t)b * 8 + h) * 128 + w * 16 + l] = ph;
        }
    }

    int rb = 0;   // src base toggle; dst = rb ^ BUFB

    for (int t = 0; t < 127; ++t) {
        const int m = 127 - t - 16 * h;
        if (m <= 0) break;
        const int mm = (m > 16) ? 16 : m;
        const bool doExpN = (h >= 1) && (126 - t >= 16 * h);
        const bool doImpT = (h < 7) && (t <= 110 - 16 * h);
        const int rw = rb ^ BUFB;

        // ---- export-slot reuse gate (ring depth 2), per wave, lane 0 ----
        if (doExpN && t >= 1 && l == 0) {
            while (__hip_atomic_load(ackC, __ATOMIC_RELAXED, __HIP_MEMORY_SCOPE_AGENT) < t - 1)
                __builtin_amdgcn_s_sleep(1);
        }

        // ---- MFMA: 4-tile partials over this wave's K-half + gate split-K ----
        f32x4 p0 = {}, p1 = {}, p2 = {}, p3 = {}, ag = {};
#define STEP(i) { \
            half8 av = *(const half8*)(lds + (rd##i ^ rb)); \
            p0 = MFMA16(av, W0_##i, p0, 0, 0, 0); \
            p1 = MFMA16(av, W1_##i, p1, 0, 0, 0); \
            p2 = MFMA16(av, W2_##i, p2, 0, 0, 0); \
            p3 = MFMA16(av, W3_##i, p3, 0, 0, 0); \
            if ((i >> 1) == g) \
                ag = MFMA16((i & 1) ? WG1 : WG0, av, ag, 0, 0, 0); }
        STEP(0) STEP(1) STEP(2) STEP(3) STEP(4) STEP(5) STEP(6) STEP(7)
#undef STEP

        // ---- write partner's 2 tiles + gate partial -> LDS ----
        if (khalf == 0) {
            *(f32x4*)(lds + PSLOT(2)) = p2;
            *(f32x4*)(lds + PSLOT(3)) = p3;
        } else {
            *(f32x4*)(lds + PSLOT(0)) = p0;
            *(f32x4*)(lds + PSLOT(1)) = p1;
        }
        if (l < 16) *(f32x4*)(lds + gwo) = ag;

        LDS_BARRIER();   // MID: partials + gate partials visible (LDS-only)

        // ---- combine own-tile partials ----
        f32x4 a0, a1;
        if (khalf == 0) {
            a0 = p0 + *(const f32x4*)(lds + PSLOT(0));
            a1 = p1 + *(const f32x4*)(lds + PSLOT(1));
        } else {
            a0 = p2 + *(const f32x4*)(lds + PSLOT(2));
            a1 = p3 + *(const f32x4*)(lds + PSLOT(3));
        }

        // ---- deterministic gate sum + in-lane softmax -> sgbuf (lanes 0..15) ----
        if (l < 16) {
            float s0g = gbi0, s1g = gbi1, s2g = gbi2;
            #pragma unroll
            for (int w8 = 0; w8 < 8; ++w8) {
                f32x4 v = *(const f32x4*)(lds + GBUF + (w8 * 16 + l) * 16);
                s0g += v[0]; s1g += v[1]; s2g += v[2];
            }
            float mg = fmaxf(fmaxf(s0g, s1g), s2g);
            float ee0 = __builtin_amdgcn_exp2f((s0g - mg) * LOG2E);
            float ee1 = __builtin_amdgcn_exp2f((s1g - mg) * LOG2E);
            float ee2 = __builtin_amdgcn_exp2f((s2g - mg) * LOG2E);
            float inv = __builtin_amdgcn_rcpf(ee0 + ee1 + ee2);
            float* sp = (float*)(lds + sgw + l * 12);
            sp[0] = ee0 * inv; sp[1] = ee1 * inv; sp[2] = ee2 * inv;
        }
        // within-wave ordering: sgbuf writes complete before broadcast reads
        asm volatile("s_waitcnt lgkmcnt(0)" ::: "memory");
        __builtin_amdgcn_sched_barrier(0);
        // broadcast read: rows q*4..q*4+3, 3 gates each (48B, same addr per group)
        f32x4 v0 = *(const f32x4*)(lds + sgw + q * 48);
        f32x4 v1 = *(const f32x4*)(lds + sgw + q * 48 + 16);
        f32x4 v2 = *(const f32x4*)(lds + sgw + q * 48 + 32);
        float g0a[4] = { v0[0], v0[3], v1[2], v2[1] };
        float g1a[4] = { v0[1], v1[0], v1[3], v2[2] };
        float g2a[4] = { v0[2], v1[1], v2[0], v2[3] };

        // ---- boundary rv (row 16, fp16) + next-q-group row-0 carry (fp32) ----
        float b0 = (float)*(const _Float16*)(lds + (bnd0 ^ rb));
        float b1 = (float)*(const _Float16*)(lds + (bnd1 ^ rb));
        float s0 = __shfl(cv0[0], (l + 16) & 63, 64);
        float s1 = __shfl(cv1[0], (l + 16) & 63, 64);

        // ---- epilogue (exports = self-signaling tagged u64 granules) ----
        const unsigned long long tagv = (unsigned long long)(t + 1) << 32;
        float cm0 = -3.4e38f, cm1 = -3.4e38f;
        #pragma unroll
        for (int r = 0; r < 4; ++r) {
            const int row = q * 4 + r;
            float g0f = g0a[r];
            float g1f = g1a[r];
            float g2f = g2a[r];
            if (row < mm) {
                #define EPI(NT, ACC, CV, SHV, BV, WBV, CMV) {                                \
                    float pre = ACC[r] + WBV;                                                \
                    float exx = __builtin_amdgcn_exp2f(pre * (2.f * LOG2E));                 \
                    float ce = 1.f - 2.f * __builtin_amdgcn_rcpf(exx + 1.f);                 \
                    float lv = CV[r];                                                        \
                    float rv = (r < 3) ? CV[(r < 3) ? r + 1 : 0] : (q < 3 ? SHV : BV);       \
                    float nx = g0f * lv + g1f * ce + g2f * rv;                               \
                    CMV = fmaxf(CMV, nx);                                                    \
                    _Float16 nh = (_Float16)nx;                                              \
                    CV[r] = nx;   /* FP32 carry: no per-level rounding */                    \
                    int pdi = __builtin_amdgcn_update_dpp(                                   \
                        0, __builtin_bit_cast(int, nx), 0xB1, 0xF, 0xF, true);               \
                    float pnx = __builtin_bit_cast(float, pdi);                              \
                    unsigned pk = (unsigned)__builtin_bit_cast(unsigned short, nh)           \
                        | ((unsigned)__builtin_bit_cast(unsigned short, (_Float16)pnx) << 16);\
                    if (!(lr & 1)) {                                                         \
                        *(unsigned*)(lds + (wo[NT][r] ^ rw)) = pk;                           \
                        if (r == 0 && q == 0 && doExpN) {                                    \
                            unsigned long long* ep = brow +                                  \
                                (((size_t)((t + 1) & 1) * 32 + b) * 8 + h) * 128             \
                                + (cw >> 1) + NT * 8 + (lr >> 1);                            \
                            __hip_atomic_store(ep, (unsigned long long)pk | tagv,            \
                                               __ATOMIC_RELAXED, __HIP_MEMORY_SCOPE_AGENT);  \
                        }                                                                    \
                    }                                                                        \
                }
                EPI(0, a0, cv0, s0, b0, wb0, cm0)
                EPI(1, a1, cv1, s1, b1, wb1, cm1)
                #undef EPI
            }
        }

        // ---- wave 0: first-try granule loads (overlap with cm-reduce) ----
        unsigned long long g0v = 0, g1v = 0;
        const unsigned long long* bp = nullptr;
        if (w == 0 && doImpT) {
            bp = brow + (((size_t)((t + 1) & 1) * 32 + b) * 8 + (h + 1)) * 128 + 2 * l;
            g0v = __hip_atomic_load(bp,     __ATOMIC_RELAXED, __HIP_MEMORY_SCOPE_AGENT);
            g1v = __hip_atomic_load(bp + 1, __ATOMIC_RELAXED, __HIP_MEMORY_SCOPE_AGENT);
        }

        // ---- col-max -> private pmax slot (overlaps the granule loads) ----
        cm0 = fmaxf(cm0, __shfl_xor(cm0, 16, 64));
        cm0 = fmaxf(cm0, __shfl_xor(cm0, 32, 64));
        cm1 = fmaxf(cm1, __shfl_xor(cm1, 16, 64));
        cm1 = fmaxf(cm1, __shfl_xor(cm1, 32, 64));
        if (l < 16) {
            unsigned ph = (unsigned)__builtin_bit_cast(unsigned short, (_Float16)cm0)
                        | ((unsigned)__builtin_bit_cast(unsigned short, (_Float16)cm1) << 16);
            pmax[((size_t)b * PS_SLOTS + slotbase + t) * 128 + w * 16 + l] = ph;
        }

        // ---- wave 0: poll tags, land import into DST row 16, ack ----
        if (w == 0 && doImpT) {
            const unsigned tag = (unsigned)(t + 1);
            while ((unsigned)(g0v >> 32) != tag) {
                __builtin_amdgcn_s_sleep(1);
                g0v = __hip_atomic_load(bp, __ATOMIC_RELAXED, __HIP_MEMORY_SCOPE_AGENT);
            }
            while ((unsigned)(g1v >> 32) != tag) {
                __builtin_amdgcn_s_sleep(1);
                g1v = __hip_atomic_load(bp + 1, __ATOMIC_RELAXED, __HIP_MEMORY_SCOPE_AGENT);
            }
            unsigned long long data = (g0v & 0xffffffffull) | (g1v << 32);
            *(unsigned long long*)(lds + (impA ^ rw)) = data;
            if (l == 0)
                __hip_atomic_store(ackP, t + 1, __ATOMIC_RELAXED, __HIP_MEMORY_SCOPE_AGENT);
        }

        LDS_BARRIER();   // END: dst rows + import visible (LDS-only)
        rb ^= BUFB;
    }
}

extern "C" void kernel_launch(void* const* d_in, const int* in_sizes, int n_in,
                              void* d_out, int out_size, void* d_ws, size_t ws_size,
                              hipStream_t stream) {
    const float* x  = (const float*)d_in[0];
    const float* Wl = (const float*)d_in[1];
    const float* Wr = (const float*)d_in[2];
    const float* Wb = (const float*)d_in[3];
    const float* Gl = (const float*)d_in[4];
    const float* Gr = (const float*)d_in[5];
    const float* Gb = (const float*)d_in[6];
    float* out = (float*)d_out;
    char* ws = (char*)d_ws;

    _Float16* WT = (_Float16*)ws;                                  // 278,528 B
    unsigned long long* brow = (unsigned long long*)(ws + 278528); // 524,288 B (ring 2, tagged)
    int* flags = (int*)(ws + 802816);                              // 32,768 B (acks)
    unsigned* pmax = (unsigned*)(ws + 835584);                     // 9,306,112 + 131,072 B (pmax + pmax0)

    prep_wt<<<272, 256, 0, stream>>>(Wl, Wr, Gl, Gr, WT);
    init_misc<<<B_, 256, 0, stream>>>(flags, brow);

    void* args[] = { (void*)&x, (void*)&WT, (void*)&Wb, (void*)&Gb,
                     (void*)&pmax, (void*)&brow, (void*)&flags };
    hipLaunchCooperativeKernel((const void*)grcnn_main, dim3(B_ * 8), dim3(NTHR),
                               args, 0, stream);

    decode_out<<<1024, 256, 0, stream>>>(pmax, out);
}

// Round 20
// 371.635 us; speedup vs baseline: 1.2105x; 1.0390x over previous
//
#include <hip/hip_runtime.h>

// GrCNN: B=32, L=128, D=256, 127 sequential levels.
// Round 20: = round 19 (passed, 386us; main 355us) with the cross-block
// protocol loosened -- computation bit-identical:
//  - RING 2 -> 4 for the tagged-granule exchange (slot (t+1)&3, brow 1MB,
//    ack gate ackC >= t-3). Ring-2 forced producer/consumer lockstep from
//    both sides; ring-4 gives 3 levels of elastic slack so the ack poll is
//    almost always immediate.
//  - ACK GATE MOVED to just before the epilogue exports (was: top of level,
//    blocking the wave before MFMA). MFMA+softmax now run ahead of any
//    cross-block dependency.
// tag-in-data u64 granules (1 L3 round trip), K-split pairing, fp32 carries,
// pinned W (AGPR-resident), sgbuf gate broadcast, LDS-only barriers,
// in-main level-0 max, pmax+decode identical to r19.

#define B_ 32
#define L_ 128
#define D_ 256
#define NTHR 512
#define BUFB 16384
#define GBUF 25088            // gbuf: [w][16] f32x4 = 2048 B
#define PEX  27136            // pexch: [g][tile][lane] f32x4 = 16384 B
#define SGB  43520            // sgbuf: [w][16][3] float = 1536 B
#define LOG2E 1.4426950408889634f
#define PS_SLOTS 568          // sum_{h=0}^{7} (127-16h)
#define BROW_U64 131072       // 4 slots * 32 b * 8 h * 128 granules (1 MB)

typedef _Float16 half8 __attribute__((ext_vector_type(8)));
typedef float f32x4 __attribute__((ext_vector_type(4)));
typedef unsigned u32x4 __attribute__((ext_vector_type(4)));

#define SWZ(o)  ((o) ^ ((((o) >> 9) & 7) << 4))
#define MFMA16 __builtin_amdgcn_mfma_f32_16x16x32_f16
// LDS-only barrier: no vmcnt drain (granule stores are self-signaling;
// pmax has no intra-kernel consumer)
#define LDS_BARRIER() asm volatile("s_waitcnt lgkmcnt(0)\n\ts_barrier" ::: "memory")

// 32-bit-component register pin (r13-verified: stays resident, no remat)
#define PIN(H) { \
    u32x4 t_ = __builtin_bit_cast(u32x4, H); \
    unsigned p0_ = t_[0], p1_ = t_[1], p2_ = t_[2], p3_ = t_[3]; \
    asm volatile("" : "+v"(p0_), "+v"(p1_), "+v"(p2_), "+v"(p3_)); \
    t_[0] = p0_; t_[1] = p1_; t_[2] = p2_; t_[3] = p3_; \
    H = __builtin_bit_cast(half8, t_); }

// ---- WT[272][512] fp16: col j -> 512 k (k<256: Wl/Gl row k, else Wr/Gr) ----
__global__ void prep_wt(const float* __restrict__ Wl, const float* __restrict__ Wr,
                        const float* __restrict__ Gl, const float* __restrict__ Gr,
                        _Float16* __restrict__ WT) {
    int j = blockIdx.x;
    for (int k = threadIdx.x; k < 512; k += 256) {
        float v = 0.f;
        if (j < 256) v = (k < 256) ? Wl[k * 256 + j] : Wr[(k - 256) * 256 + j];
        else { int jj = j - 256; if (jj < 3) v = (k < 256) ? Gl[k * 3 + jj] : Gr[(k - 256) * 3 + jj]; }
        WT[(size_t)j * 512 + k] = (_Float16)v;
    }
}

// ---- init: zero acks + brow only ----
__global__ void init_misc(int* __restrict__ flags, unsigned long long* __restrict__ brow) {
    int b = blockIdx.x, c = threadIdx.x;
    if (b == 0) for (int i = c; i < 2 * 256 * 16; i += 256) flags[i] = 0;
    for (int i = b * 256 + c; i < BROW_U64; i += 32 * 256) brow[i] = 0ull;
}

// ---- decode: pmax/pmax0 partials -> out levels 0..127 ----
__global__ void decode_out(const unsigned* __restrict__ pmax, float* __restrict__ out) {
    const unsigned* pmax0 = pmax + (size_t)32 * PS_SLOTS * 128;  // [b][h][128]
    for (size_t i = (size_t)blockIdx.x * 256 + threadIdx.x; i < (size_t)32 * 128 * 256;
         i += (size_t)gridDim.x * 256) {
        int c = (int)(i & 255);
        int k = (int)((i >> 8) & 127);
        int b = (int)(i / (128 * 256));
        // c = 64g + 32khalf + 16NT + lr; w = 4khalf+g; dw = w*16+lr
        int dw = ((c >> 5) & 1) * 64 + ((c >> 6) & 3) * 16 + (c & 15);
        int hi = (c >> 4) & 1;                  // NT
        float mx = -3.4e38f;
        if (k == 0) {
            #pragma unroll
            for (int h = 0; h < 8; ++h) {
                unsigned u = pmax0[((size_t)b * 8 + h) * 128 + dw];
                unsigned short us = hi ? (unsigned short)(u >> 16) : (unsigned short)(u & 0xffff);
                mx = fmaxf(mx, (float)__builtin_bit_cast(_Float16, us));
            }
        } else {
            int hcnt = (143 - k) >> 4;          // ceil((128-k)/16)
            for (int h = 0; h < hcnt; ++h) {
                int slot = 127 * h - 8 * h * (h - 1) + (k - 1);
                unsigned u = pmax[((size_t)b * PS_SLOTS + slot) * 128 + dw];
                unsigned short us = hi ? (unsigned short)(u >> 16) : (unsigned short)(u & 0xffff);
                mx = fmaxf(mx, (float)__builtin_bit_cast(_Float16, us));
            }
        }
        out[((size_t)b * 128 + k) * 256 + c] = mx;
    }
}

__global__ __launch_bounds__(NTHR, 2) void grcnn_main(
    const float* __restrict__ x, const _Float16* __restrict__ WT,
    const float* __restrict__ Wb, const float* __restrict__ Gb,
    unsigned* __restrict__ pmax, unsigned long long* __restrict__ brow,
    int* __restrict__ flags)
{
    __shared__ alignas(16) char lds[SGB + 1536];  // bufA@0, bufB, gbuf, pexch, sgbuf

    const int tid = threadIdx.x;
    const int b = blockIdx.x & 31, h = blockIdx.x >> 5;
    const int w = tid >> 6, l = tid & 63, lr = l & 15, q = l >> 4;
    const int g = w & 3, khalf = w >> 2;
    const int cw = g * 64 + khalf * 32;     // wave's epilogue 32-col slab

    // ---- W fragments: 4 tiles x 8 ksteps of this wave's K-half, pinned ----
    const _Float16* wtb0 = WT + (size_t)(64 * g + lr) * 512 + khalf * 256 + q * 8;
    const _Float16* wtb1 = WT + (size_t)(64 * g + 16 + lr) * 512 + khalf * 256 + q * 8;
    const _Float16* wtb2 = WT + (size_t)(64 * g + 32 + lr) * 512 + khalf * 256 + q * 8;
    const _Float16* wtb3 = WT + (size_t)(64 * g + 48 + lr) * 512 + khalf * 256 + q * 8;
#define LDW1(T, i) half8 W##T##_##i = *(const half8*)(wtb##T + i * 32); PIN(W##T##_##i)
#define LDWT(T) LDW1(T,0) LDW1(T,1) LDW1(T,2) LDW1(T,3) LDW1(T,4) LDW1(T,5) LDW1(T,6) LDW1(T,7)
    LDWT(0) LDWT(1) LDWT(2) LDWT(3)
#undef LDWT
#undef LDW1
    // gate frags: global ksteps 8*khalf + {2g, 2g+1} (union over waves = all 16)
    const _Float16* wpg = WT + (size_t)(256 + lr) * 512 + q * 8;
    const half8 WG0 = *(const half8*)(wpg + (8 * khalf + 2 * g) * 32);
    const half8 WG1 = *(const half8*)(wpg + (8 * khalf + 2 * g + 1) * 32);

    const float wb0 = Wb[cw + lr], wb1 = Wb[cw + 16 + lr];
    const float gbi0 = Gb[0], gbi1 = Gb[1], gbi2 = Gb[2];

    // ---- precomputed LDS addresses ----
#define RDA(i) const int rd##i = SWZ(lr * 512 + (8 * khalf + i) * 64 + q * 16);
    RDA(0) RDA(1) RDA(2) RDA(3) RDA(4) RDA(5) RDA(6) RDA(7)
#undef RDA
    int wo[2][4];
    #pragma unroll
    for (int nt = 0; nt < 2; ++nt)
        #pragma unroll
        for (int r = 0; r < 4; ++r)
            wo[nt][r] = SWZ((q * 4 + r) * 512 + (cw + nt * 16 + lr) * 2);
    const int impA = 8192 + l * 8;               // row 16 (identity swizzle)
    const int bnd0 = 8192 + (cw + lr) * 2;       // boundary u16 (identity swizzle)
    const int bnd1 = 8192 + (cw + 16 + lr) * 2;
    const int gwo = GBUF + (w * 16 + lr) * 16;   // gate partial slot
    const int sgw = SGB + w * 192;               // this wave's sgbuf slice
#define PSLOT(T) (PEX + (((g * 4 + (T)) * 64 + l) * 16))

    int* ackP  = &flags[(256 + b * 8 + h) * 16];
    int* ackC  = &flags[(256 + b * 8 + h - 1) * 16];
    const int slotbase = 127 * h - 8 * h * (h - 1);
    unsigned* pmax0 = pmax + (size_t)32 * PS_SLOTS * 128;

    // ---- stage rows 16h..16h+16 (clamped) into BOTH buffers ----
    for (int ch = tid; ch < 17 * 32; ch += NTHR) {
        int row = ch >> 5, kc = ch & 31;
        int grow = 16 * h + row; if (grow > 127) grow = 127;
        const float* xp = x + ((size_t)b * L_ + grow) * D_ + kc * 8;
        half8 v;
        #pragma unroll
        for (int j = 0; j < 8; ++j) v[j] = (_Float16)xp[j];
        int off = SWZ(row * 512 + kc * 16);
        *(half8*)(lds + off) = v;
        *(half8*)(lds + BUFB + off) = v;
    }
    __syncthreads();

    // ---- init lv/rv carries from staged state (rows q*4..q*4+3, 2 cols) ----
    float cv0[4], cv1[4];
    #pragma unroll
    for (int i = 0; i < 4; ++i) {
        cv0[i] = (float)*(const _Float16*)(lds + SWZ((q * 4 + i) * 512 + (cw + lr) * 2));
        cv1[i] = (float)*(const _Float16*)(lds + SWZ((q * 4 + i) * 512 + (cw + 16 + lr) * 2));
    }

    // ---- level-0 col-max from carries -> pmax0[b][h] ----
    {
        float c0 = fmaxf(fmaxf(cv0[0], cv0[1]), fmaxf(cv0[2], cv0[3]));
        float c1 = fmaxf(fmaxf(cv1[0], cv1[1]), fmaxf(cv1[2], cv1[3]));
        c0 = fmaxf(c0, __shfl_xor(c0, 16, 64)); c0 = fmaxf(c0, __shfl_xor(c0, 32, 64));
        c1 = fmaxf(c1, __shfl_xor(c1, 16, 64)); c1 = fmaxf(c1, __shfl_xor(c1, 32, 64));
        if (l < 16) {
            unsigned ph = (unsigned)__builtin_bit_cast(unsigned short, (_Float16)c0)
                        | ((unsigned)__builtin_bit_cast(unsigned short, (_Float16)c1) << 16);
            pmax0[((size_t)b * 8 + h) * 128 + w * 16 + l] = ph;
        }
    }

    int rb = 0;   // src base toggle; dst = rb ^ BUFB

    for (int t = 0; t < 127; ++t) {
        const int m = 127 - t - 16 * h;
        if (m <= 0) break;
        const int mm = (m > 16) ? 16 : m;
        const bool doExpN = (h >= 1) && (126 - t >= 16 * h);
        const bool doImpT = (h < 7) && (t <= 110 - 16 * h);
        const int rw = rb ^ BUFB;

        // ---- MFMA: 4-tile partials over this wave's K-half + gate split-K ----
        f32x4 p0 = {}, p1 = {}, p2 = {}, p3 = {}, ag = {};
#define STEP(i) { \
            half8 av = *(const half8*)(lds + (rd##i ^ rb)); \
            p0 = MFMA16(av, W0_##i, p0, 0, 0, 0); \
            p1 = MFMA16(av, W1_##i, p1, 0, 0, 0); \
            p2 = MFMA16(av, W2_##i, p2, 0, 0, 0); \
            p3 = MFMA16(av, W3_##i, p3, 0, 0, 0); \
            if ((i >> 1) == g) \
                ag = MFMA16((i & 1) ? WG1 : WG0, av, ag, 0, 0, 0); }
        STEP(0) STEP(1) STEP(2) STEP(3) STEP(4) STEP(5) STEP(6) STEP(7)
#undef STEP

        // ---- write partner's 2 tiles + gate partial -> LDS ----
        if (khalf == 0) {
            *(f32x4*)(lds + PSLOT(2)) = p2;
            *(f32x4*)(lds + PSLOT(3)) = p3;
        } else {
            *(f32x4*)(lds + PSLOT(0)) = p0;
            *(f32x4*)(lds + PSLOT(1)) = p1;
        }
        if (l < 16) *(f32x4*)(lds + gwo) = ag;

        LDS_BARRIER();   // MID: partials + gate partials visible (LDS-only)

        // ---- combine own-tile partials ----
        f32x4 a0, a1;
        if (khalf == 0) {
            a0 = p0 + *(const f32x4*)(lds + PSLOT(0));
            a1 = p1 + *(const f32x4*)(lds + PSLOT(1));
        } else {
            a0 = p2 + *(const f32x4*)(lds + PSLOT(2));
            a1 = p3 + *(const f32x4*)(lds + PSLOT(3));
        }

        // ---- deterministic gate sum + in-lane softmax -> sgbuf (lanes 0..15) ----
        if (l < 16) {
            float s0g = gbi0, s1g = gbi1, s2g = gbi2;
            #pragma unroll
            for (int w8 = 0; w8 < 8; ++w8) {
                f32x4 v = *(const f32x4*)(lds + GBUF + (w8 * 16 + l) * 16);
                s0g += v[0]; s1g += v[1]; s2g += v[2];
            }
            float mg = fmaxf(fmaxf(s0g, s1g), s2g);
            float ee0 = __builtin_amdgcn_exp2f((s0g - mg) * LOG2E);
            float ee1 = __builtin_amdgcn_exp2f((s1g - mg) * LOG2E);
            float ee2 = __builtin_amdgcn_exp2f((s2g - mg) * LOG2E);
            float inv = __builtin_amdgcn_rcpf(ee0 + ee1 + ee2);
            float* sp = (float*)(lds + sgw + l * 12);
            sp[0] = ee0 * inv; sp[1] = ee1 * inv; sp[2] = ee2 * inv;
        }
        // within-wave ordering: sgbuf writes complete before broadcast reads
        asm volatile("s_waitcnt lgkmcnt(0)" ::: "memory");
        __builtin_amdgcn_sched_barrier(0);
        // broadcast read: rows q*4..q*4+3, 3 gates each (48B, same addr per group)
        f32x4 v0 = *(const f32x4*)(lds + sgw + q * 48);
        f32x4 v1 = *(const f32x4*)(lds + sgw + q * 48 + 16);
        f32x4 v2 = *(const f32x4*)(lds + sgw + q * 48 + 32);
        float g0a[4] = { v0[0], v0[3], v1[2], v2[1] };
        float g1a[4] = { v0[1], v1[0], v1[3], v2[2] };
        float g2a[4] = { v0[2], v1[1], v2[0], v2[3] };

        // ---- boundary rv (row 16, fp16) + next-q-group row-0 carry (fp32) ----
        float b0 = (float)*(const _Float16*)(lds + (bnd0 ^ rb));
        float b1 = (float)*(const _Float16*)(lds + (bnd1 ^ rb));
        float s0 = __shfl(cv0[0], (l + 16) & 63, 64);
        float s1 = __shfl(cv1[0], (l + 16) & 63, 64);

        // ---- export-slot reuse gate (ring depth 4), moved post-MFMA ----
        if (doExpN && t >= 3 && l == 0) {
            while (__hip_atomic_load(ackC, __ATOMIC_RELAXED, __HIP_MEMORY_SCOPE_AGENT) < t - 3)
                __builtin_amdgcn_s_sleep(1);
        }

        // ---- epilogue (exports = self-signaling tagged u64 granules) ----
        const unsigned long long tagv = (unsigned long long)(t + 1) << 32;
        float cm0 = -3.4e38f, cm1 = -3.4e38f;
        #pragma unroll
        for (int r = 0; r < 4; ++r) {
            const int row = q * 4 + r;
            float g0f = g0a[r];
            float g1f = g1a[r];
            float g2f = g2a[r];
            if (row < mm) {
                #define EPI(NT, ACC, CV, SHV, BV, WBV, CMV) {                                \
                    float pre = ACC[r] + WBV;                                                \
                    float exx = __builtin_amdgcn_exp2f(pre * (2.f * LOG2E));                 \
                    float ce = 1.f - 2.f * __builtin_amdgcn_rcpf(exx + 1.f);                 \
                    float lv = CV[r];                                                        \
                    float rv = (r < 3) ? CV[(r < 3) ? r + 1 : 0] : (q < 3 ? SHV : BV);       \
                    float nx = g0f * lv + g1f * ce + g2f * rv;                               \
                    CMV = fmaxf(CMV, nx);                                                    \
                    _Float16 nh = (_Float16)nx;                                              \
                    CV[r] = nx;   /* FP32 carry: no per-level rounding */                    \
                    int pdi = __builtin_amdgcn_update_dpp(                                   \
                        0, __builtin_bit_cast(int, nx), 0xB1, 0xF, 0xF, true);               \
                    float pnx = __builtin_bit_cast(float, pdi);                              \
                    unsigned pk = (unsigned)__builtin_bit_cast(unsigned short, nh)           \
                        | ((unsigned)__builtin_bit_cast(unsigned short, (_Float16)pnx) << 16);\
                    if (!(lr & 1)) {                                                         \
                        *(unsigned*)(lds + (wo[NT][r] ^ rw)) = pk;                           \
                        if (r == 0 && q == 0 && doExpN) {                                    \
                            unsigned long long* ep = brow +                                  \
                                (((size_t)((t + 1) & 3) * 32 + b) * 8 + h) * 128             \
                                + (cw >> 1) + NT * 8 + (lr >> 1);                            \
                            __hip_atomic_store(ep, (unsigned long long)pk | tagv,            \
                                               __ATOMIC_RELAXED, __HIP_MEMORY_SCOPE_AGENT);  \
                        }                                                                    \
                    }                                                                        \
                }
                EPI(0, a0, cv0, s0, b0, wb0, cm0)
                EPI(1, a1, cv1, s1, b1, wb1, cm1)
                #undef EPI
            }
        }

        // ---- wave 0: first-try granule loads (overlap with cm-reduce) ----
        unsigned long long g0v = 0, g1v = 0;
        const unsigned long long* bp = nullptr;
        if (w == 0 && doImpT) {
            bp = brow + (((size_t)((t + 1) & 3) * 32 + b) * 8 + (h + 1)) * 128 + 2 * l;
            g0v = __hip_atomic_load(bp,     __ATOMIC_RELAXED, __HIP_MEMORY_SCOPE_AGENT);
            g1v = __hip_atomic_load(bp + 1, __ATOMIC_RELAXED, __HIP_MEMORY_SCOPE_AGENT);
        }

        // ---- col-max -> private pmax slot (overlaps the granule loads) ----
        cm0 = fmaxf(cm0, __shfl_xor(cm0, 16, 64));
        cm0 = fmaxf(cm0, __shfl_xor(cm0, 32, 64));
        cm1 = fmaxf(cm1, __shfl_xor(cm1, 16, 64));
        cm1 = fmaxf(cm1, __shfl_xor(cm1, 32, 64));
        if (l < 16) {
            unsigned ph = (unsigned)__builtin_bit_cast(unsigned short, (_Float16)cm0)
                        | ((unsigned)__builtin_bit_cast(unsigned short, (_Float16)cm1) << 16);
            pmax[((size_t)b * PS_SLOTS + slotbase + t) * 128 + w * 16 + l] = ph;
        }

        // ---- wave 0: poll tags, land import into DST row 16, ack ----
        if (w == 0 && doImpT) {
            const unsigned tag = (unsigned)(t + 1);
            while ((unsigned)(g0v >> 32) != tag) {
                __builtin_amdgcn_s_sleep(1);
                g0v = __hip_atomic_load(bp, __ATOMIC_RELAXED, __HIP_MEMORY_SCOPE_AGENT);
            }
            while ((unsigned)(g1v >> 32) != tag) {
                __builtin_amdgcn_s_sleep(1);
                g1v = __hip_atomic_load(bp + 1, __ATOMIC_RELAXED, __HIP_MEMORY_SCOPE_AGENT);
            }
            unsigned long long data = (g0v & 0xffffffffull) | (g1v << 32);
            *(unsigned long long*)(lds + (impA ^ rw)) = data;
            if (l == 0)
                __hip_atomic_store(ackP, t + 1, __ATOMIC_RELAXED, __HIP_MEMORY_SCOPE_AGENT);
        }

        LDS_BARRIER();   // END: dst rows + import visible (LDS-only)
        rb ^= BUFB;
    }
}

extern "C" void kernel_launch(void* const* d_in, const int* in_sizes, int n_in,
                              void* d_out, int out_size, void* d_ws, size_t ws_size,
                              hipStream_t stream) {
    const float* x  = (const float*)d_in[0];
    const float* Wl = (const float*)d_in[1];
    const float* Wr = (const float*)d_in[2];
    const float* Wb = (const float*)d_in[3];
    const float* Gl = (const float*)d_in[4];
    const float* Gr = (const float*)d_in[5];
    const float* Gb = (const float*)d_in[6];
    float* out = (float*)d_out;
    char* ws = (char*)d_ws;

    _Float16* WT = (_Float16*)ws;                                  // 278,528 B
    unsigned long long* brow = (unsigned long long*)(ws + 278528); // 1,048,576 B (ring 4, tagged)
    int* flags = (int*)(ws + 1327104);                             // 32,768 B (acks)
    unsigned* pmax = (unsigned*)(ws + 1359872);                    // 9,306,112 + 131,072 B

    prep_wt<<<272, 256, 0, stream>>>(Wl, Wr, Gl, Gr, WT);
    init_misc<<<B_, 256, 0, stream>>>(flags, brow);

    void* args[] = { (void*)&x, (void*)&WT, (void*)&Wb, (void*)&Gb,
                     (void*)&pmax, (void*)&brow, (void*)&flags };
    hipLaunchCooperativeKernel((const void*)grcnn_main, dim3(B_ * 8), dim3(NTHR),
                               args, 0, stream);

    decode_out<<<1024, 256, 0, stream>>>(pmax, out);
}

// Round 21
// 331.771 us; speedup vs baseline: 1.3559x; 1.1202x over previous
//
#include <hip/hip_runtime.h>

// GrCNN: B=32, L=128, D=256, 127 sequential levels.
// Round 21: = round 20 (passed, 372us; main 338us) with the MID barrier
// ELIMINATED -- one barrier per level:
//  - central tiles back to full-K per wave (16 ds_read_b128, 2 col-tiles,
//    single accumulation chain; wave w owns cols [32w,32w+32)) -> no pexch.
//  - gate MFMA fully in-wave: ag accumulated over all 16 ksteps with the
//    same av loads; 16 gate A-fragments (16KB) staged ONCE into LDS (space
//    freed by pexch+gbuf), read conflict-free (stride-16B b128). Lanes 0..15
//    hold complete preacts -> in-lane softmax -> within-wave sgbuf broadcast.
//    No cross-wave data inside a level => MID barrier deleted.
// Protocol byte-identical to r20: tag-in-data u64 granules (ring 4, ack gate
// post-MFMA), LDS-only END barrier, fp32 carries, pinned W (128 regs,
// AGPR-resident), in-main level-0 max, pmax+decode (dw formula reverted to
// the cw=32w wave->col map).

#define B_ 32
#define L_ 128
#define D_ 256
#define NTHR 512
#define BUFB 16384
#define SGB  9216             // sgbuf: [w][16][3] float = 1536 B (in buf gap)
#define GWT  25088            // gate A-fragments: [16][64]*16B = 16384 B
#define LOG2E 1.4426950408889634f
#define PS_SLOTS 568          // sum_{h=0}^{7} (127-16h)
#define BROW_U64 131072       // 4 slots * 32 b * 8 h * 128 granules (1 MB)

typedef _Float16 half8 __attribute__((ext_vector_type(8)));
typedef float f32x4 __attribute__((ext_vector_type(4)));
typedef unsigned u32x4 __attribute__((ext_vector_type(4)));

#define SWZ(o)  ((o) ^ ((((o) >> 9) & 7) << 4))
#define MFMA16 __builtin_amdgcn_mfma_f32_16x16x32_f16
// LDS-only barrier: no vmcnt drain (granule stores are self-signaling;
// pmax has no intra-kernel consumer)
#define LDS_BARRIER() asm volatile("s_waitcnt lgkmcnt(0)\n\ts_barrier" ::: "memory")

// 32-bit-component register pin (r13-verified: stays resident, no remat)
#define PIN(H) { \
    u32x4 t_ = __builtin_bit_cast(u32x4, H); \
    unsigned p0_ = t_[0], p1_ = t_[1], p2_ = t_[2], p3_ = t_[3]; \
    asm volatile("" : "+v"(p0_), "+v"(p1_), "+v"(p2_), "+v"(p3_)); \
    t_[0] = p0_; t_[1] = p1_; t_[2] = p2_; t_[3] = p3_; \
    H = __builtin_bit_cast(half8, t_); }

// ---- WT[272][512] fp16: col j -> 512 k (k<256: Wl/Gl row k, else Wr/Gr) ----
__global__ void prep_wt(const float* __restrict__ Wl, const float* __restrict__ Wr,
                        const float* __restrict__ Gl, const float* __restrict__ Gr,
                        _Float16* __restrict__ WT) {
    int j = blockIdx.x;
    for (int k = threadIdx.x; k < 512; k += 256) {
        float v = 0.f;
        if (j < 256) v = (k < 256) ? Wl[k * 256 + j] : Wr[(k - 256) * 256 + j];
        else { int jj = j - 256; if (jj < 3) v = (k < 256) ? Gl[k * 3 + jj] : Gr[(k - 256) * 3 + jj]; }
        WT[(size_t)j * 512 + k] = (_Float16)v;
    }
}

// ---- init: zero acks + brow only ----
__global__ void init_misc(int* __restrict__ flags, unsigned long long* __restrict__ brow) {
    int b = blockIdx.x, c = threadIdx.x;
    if (b == 0) for (int i = c; i < 2 * 256 * 16; i += 256) flags[i] = 0;
    for (int i = b * 256 + c; i < BROW_U64; i += 32 * 256) brow[i] = 0ull;
}

// ---- decode: pmax/pmax0 partials -> out levels 0..127 (cw=32w col map) ----
__global__ void decode_out(const unsigned* __restrict__ pmax, float* __restrict__ out) {
    const unsigned* pmax0 = pmax + (size_t)32 * PS_SLOTS * 128;  // [b][h][128]
    for (size_t i = (size_t)blockIdx.x * 256 + threadIdx.x; i < (size_t)32 * 128 * 256;
         i += (size_t)gridDim.x * 256) {
        int c = (int)(i & 255);
        int k = (int)((i >> 8) & 127);
        int b = (int)(i / (128 * 256));
        // c = 32w + 16NT + lr -> dw = w*16 + lr, hi = NT
        int dw = ((c >> 5) * 16) + (c & 15);
        int hi = (c >> 4) & 1;
        float mx = -3.4e38f;
        if (k == 0) {
            #pragma unroll
            for (int h = 0; h < 8; ++h) {
                unsigned u = pmax0[((size_t)b * 8 + h) * 128 + dw];
                unsigned short us = hi ? (unsigned short)(u >> 16) : (unsigned short)(u & 0xffff);
                mx = fmaxf(mx, (float)__builtin_bit_cast(_Float16, us));
            }
        } else {
            int hcnt = (143 - k) >> 4;          // ceil((128-k)/16)
            for (int h = 0; h < hcnt; ++h) {
                int slot = 127 * h - 8 * h * (h - 1) + (k - 1);
                unsigned u = pmax[((size_t)b * PS_SLOTS + slot) * 128 + dw];
                unsigned short us = hi ? (unsigned short)(u >> 16) : (unsigned short)(u & 0xffff);
                mx = fmaxf(mx, (float)__builtin_bit_cast(_Float16, us));
            }
        }
        out[((size_t)b * 128 + k) * 256 + c] = mx;
    }
}

__global__ __launch_bounds__(NTHR, 2) void grcnn_main(
    const float* __restrict__ x, const _Float16* __restrict__ WT,
    const float* __restrict__ Wb, const float* __restrict__ Gb,
    unsigned* __restrict__ pmax, unsigned long long* __restrict__ brow,
    int* __restrict__ flags)
{
    __shared__ alignas(16) char lds[GWT + 16384];  // buf0@0, sgbuf@9216, buf1@16384, gwt@25088

    const int tid = threadIdx.x;
    const int b = blockIdx.x & 31, h = blockIdx.x >> 5;
    const int w = tid >> 6, l = tid & 63, lr = l & 15, q = l >> 4;
    const int cw = w * 32;                  // wave's 32-col slab

    // ---- W fragments: 2 col-tiles x 16 ksteps (full K), pinned (128 regs) ----
    const _Float16* wp0 = WT + (size_t)(cw + lr) * 512 + q * 8;
    const _Float16* wp1 = WT + (size_t)(cw + 16 + lr) * 512 + q * 8;
#define LDW(s) \
    half8 WA##s = *(const half8*)(wp0 + s * 32); \
    half8 WB##s = *(const half8*)(wp1 + s * 32); \
    PIN(WA##s) PIN(WB##s)
    LDW(0) LDW(1) LDW(2) LDW(3) LDW(4) LDW(5) LDW(6) LDW(7)
    LDW(8) LDW(9) LDW(10) LDW(11) LDW(12) LDW(13) LDW(14) LDW(15)
#undef LDW

    const float wb0 = Wb[cw + lr], wb1 = Wb[cw + 16 + lr];
    const float gbi0 = Gb[0], gbi1 = Gb[1], gbi2 = Gb[2];

    // ---- precomputed LDS addresses ----
#define RDA(i) const int rd##i = SWZ(lr * 512 + i * 64 + q * 16);
    RDA(0) RDA(1) RDA(2) RDA(3) RDA(4) RDA(5) RDA(6) RDA(7)
    RDA(8) RDA(9) RDA(10) RDA(11) RDA(12) RDA(13) RDA(14) RDA(15)
#undef RDA
    int wo[2][4];
    #pragma unroll
    for (int nt = 0; nt < 2; ++nt)
        #pragma unroll
        for (int r = 0; r < 4; ++r)
            wo[nt][r] = SWZ((q * 4 + r) * 512 + (cw + nt * 16 + lr) * 2);
    const int impA = 8192 + l * 8;               // row 16 (identity swizzle)
    const int bnd0 = 8192 + (cw + lr) * 2;       // boundary u16 (identity swizzle)
    const int bnd1 = 8192 + (cw + 16 + lr) * 2;
    const int sgw = SGB + w * 192;               // this wave's sgbuf slice
    const int gva = GWT + (l << 4);              // gate frag base (stride 1024/kstep)

    int* ackP  = &flags[(256 + b * 8 + h) * 16];
    int* ackC  = &flags[(256 + b * 8 + h - 1) * 16];
    const int slotbase = 127 * h - 8 * h * (h - 1);
    unsigned* pmax0 = pmax + (size_t)32 * PS_SLOTS * 128;

    // ---- stage gate A-fragments once: gwt[kstep i][lane ll] = WT[256+llr][i*32+lq*8..] ----
    for (int ch = tid; ch < 1024; ch += NTHR) {
        int i = ch >> 6, ll = ch & 63;
        int llr = ll & 15, lq = ll >> 4;
        half8 v = *(const half8*)(WT + (size_t)(256 + llr) * 512 + i * 32 + lq * 8);
        *(half8*)(lds + GWT + ch * 16) = v;
    }
    // ---- stage rows 16h..16h+16 (clamped) into BOTH buffers ----
    for (int ch = tid; ch < 17 * 32; ch += NTHR) {
        int row = ch >> 5, kc = ch & 31;
        int grow = 16 * h + row; if (grow > 127) grow = 127;
        const float* xp = x + ((size_t)b * L_ + grow) * D_ + kc * 8;
        half8 v;
        #pragma unroll
        for (int j = 0; j < 8; ++j) v[j] = (_Float16)xp[j];
        int off = SWZ(row * 512 + kc * 16);
        *(half8*)(lds + off) = v;
        *(half8*)(lds + BUFB + off) = v;
    }
    __syncthreads();

    // ---- init lv/rv carries from staged state (rows q*4..q*4+3, 2 cols) ----
    float cv0[4], cv1[4];
    #pragma unroll
    for (int i = 0; i < 4; ++i) {
        cv0[i] = (float)*(const _Float16*)(lds + SWZ((q * 4 + i) * 512 + (cw + lr) * 2));
        cv1[i] = (float)*(const _Float16*)(lds + SWZ((q * 4 + i) * 512 + (cw + 16 + lr) * 2));
    }

    // ---- level-0 col-max from carries -> pmax0[b][h] ----
    {
        float c0 = fmaxf(fmaxf(cv0[0], cv0[1]), fmaxf(cv0[2], cv0[3]));
        float c1 = fmaxf(fmaxf(cv1[0], cv1[1]), fmaxf(cv1[2], cv1[3]));
        c0 = fmaxf(c0, __shfl_xor(c0, 16, 64)); c0 = fmaxf(c0, __shfl_xor(c0, 32, 64));
        c1 = fmaxf(c1, __shfl_xor(c1, 16, 64)); c1 = fmaxf(c1, __shfl_xor(c1, 32, 64));
        if (l < 16) {
            unsigned ph = (unsigned)__builtin_bit_cast(unsigned short, (_Float16)c0)
                        | ((unsigned)__builtin_bit_cast(unsigned short, (_Float16)c1) << 16);
            pmax0[((size_t)b * 8 + h) * 128 + w * 16 + l] = ph;
        }
    }

    int rb = 0;   // src base toggle; dst = rb ^ BUFB

    for (int t = 0; t < 127; ++t) {
        const int m = 127 - t - 16 * h;
        if (m <= 0) break;
        const int mm = (m > 16) ? 16 : m;
        const bool doExpN = (h >= 1) && (126 - t >= 16 * h);
        const bool doImpT = (h < 7) && (t <= 110 - 16 * h);
        const int rw = rb ^ BUFB;

        // ---- MFMA: 2 central tiles + in-wave gate, full K (3 chains x 16) ----
        f32x4 a0 = {}, a1 = {}, ag = {};
#define STEP(i) { \
            half8 av = *(const half8*)(lds + (rd##i ^ rb)); \
            half8 gv = *(const half8*)(lds + gva + i * 1024); \
            a0 = MFMA16(av, WA##i, a0, 0, 0, 0); \
            a1 = MFMA16(av, WB##i, a1, 0, 0, 0); \
            ag = MFMA16(gv, av, ag, 0, 0, 0); }
        STEP(0) STEP(1) STEP(2) STEP(3) STEP(4) STEP(5) STEP(6) STEP(7)
        STEP(8) STEP(9) STEP(10) STEP(11) STEP(12) STEP(13) STEP(14) STEP(15)
#undef STEP

        // ---- in-lane softmax (lanes 0..15 hold complete preacts) -> sgbuf ----
        if (l < 16) {
            float p0 = ag[0] + gbi0, p1 = ag[1] + gbi1, p2 = ag[2] + gbi2;
            float mg = fmaxf(fmaxf(p0, p1), p2);
            float ee0 = __builtin_amdgcn_exp2f((p0 - mg) * LOG2E);
            float ee1 = __builtin_amdgcn_exp2f((p1 - mg) * LOG2E);
            float ee2 = __builtin_amdgcn_exp2f((p2 - mg) * LOG2E);
            float inv = __builtin_amdgcn_rcpf(ee0 + ee1 + ee2);
            float* sp = (float*)(lds + sgw + l * 12);
            sp[0] = ee0 * inv; sp[1] = ee1 * inv; sp[2] = ee2 * inv;
        }
        // within-wave ordering: sgbuf writes complete before broadcast reads
        asm volatile("s_waitcnt lgkmcnt(0)" ::: "memory");
        __builtin_amdgcn_sched_barrier(0);
        // broadcast read: rows q*4..q*4+3, 3 gates each (48B, same addr per group)
        f32x4 v0 = *(const f32x4*)(lds + sgw + q * 48);
        f32x4 v1 = *(const f32x4*)(lds + sgw + q * 48 + 16);
        f32x4 v2 = *(const f32x4*)(lds + sgw + q * 48 + 32);
        float g0a[4] = { v0[0], v0[3], v1[2], v2[1] };
        float g1a[4] = { v0[1], v1[0], v1[3], v2[2] };
        float g2a[4] = { v0[2], v1[1], v2[0], v2[3] };

        // ---- boundary rv (row 16, fp16) + next-q-group row-0 carry (fp32) ----
        float b0 = (float)*(const _Float16*)(lds + (bnd0 ^ rb));
        float b1 = (float)*(const _Float16*)(lds + (bnd1 ^ rb));
        float s0 = __shfl(cv0[0], (l + 16) & 63, 64);
        float s1 = __shfl(cv1[0], (l + 16) & 63, 64);

        // ---- export-slot reuse gate (ring depth 4), post-MFMA ----
        if (doExpN && t >= 3 && l == 0) {
            while (__hip_atomic_load(ackC, __ATOMIC_RELAXED, __HIP_MEMORY_SCOPE_AGENT) < t - 3)
                __builtin_amdgcn_s_sleep(1);
        }

        // ---- epilogue (exports = self-signaling tagged u64 granules) ----
        const unsigned long long tagv = (unsigned long long)(t + 1) << 32;
        float cm0 = -3.4e38f, cm1 = -3.4e38f;
        #pragma unroll
        for (int r = 0; r < 4; ++r) {
            const int row = q * 4 + r;
            float g0f = g0a[r];
            float g1f = g1a[r];
            float g2f = g2a[r];
            if (row < mm) {
                #define EPI(NT, ACC, CV, SHV, BV, WBV, CMV) {                                \
                    float pre = ACC[r] + WBV;                                                \
                    float exx = __builtin_amdgcn_exp2f(pre * (2.f * LOG2E));                 \
                    float ce = 1.f - 2.f * __builtin_amdgcn_rcpf(exx + 1.f);                 \
                    float lv = CV[r];                                                        \
                    float rv = (r < 3) ? CV[(r < 3) ? r + 1 : 0] : (q < 3 ? SHV : BV);       \
                    float nx = g0f * lv + g1f * ce + g2f * rv;                               \
                    CMV = fmaxf(CMV, nx);                                                    \
                    _Float16 nh = (_Float16)nx;                                              \
                    CV[r] = nx;   /* FP32 carry: no per-level rounding */                    \
                    int pdi = __builtin_amdgcn_update_dpp(                                   \
                        0, __builtin_bit_cast(int, nx), 0xB1, 0xF, 0xF, true);               \
                    float pnx = __builtin_bit_cast(float, pdi);                              \
                    unsigned pk = (unsigned)__builtin_bit_cast(unsigned short, nh)           \
                        | ((unsigned)__builtin_bit_cast(unsigned short, (_Float16)pnx) << 16);\
                    if (!(lr & 1)) {                                                         \
                        *(unsigned*)(lds + (wo[NT][r] ^ rw)) = pk;                           \
                        if (r == 0 && q == 0 && doExpN) {                                    \
                            unsigned long long* ep = brow +                                  \
                                (((size_t)((t + 1) & 3) * 32 + b) * 8 + h) * 128             \
                                + (cw >> 1) + NT * 8 + (lr >> 1);                            \
                            __hip_atomic_store(ep, (unsigned long long)pk | tagv,            \
                                               __ATOMIC_RELAXED, __HIP_MEMORY_SCOPE_AGENT);  \
                        }                                                                    \
                    }                                                                        \
                }
                EPI(0, a0, cv0, s0, b0, wb0, cm0)
                EPI(1, a1, cv1, s1, b1, wb1, cm1)
                #undef EPI
            }
        }

        // ---- wave 0: first-try granule loads (overlap with cm-reduce) ----
        unsigned long long g0v = 0, g1v = 0;
        const unsigned long long* bp = nullptr;
        if (w == 0 && doImpT) {
            bp = brow + (((size_t)((t + 1) & 3) * 32 + b) * 8 + (h + 1)) * 128 + 2 * l;
            g0v = __hip_atomic_load(bp,     __ATOMIC_RELAXED, __HIP_MEMORY_SCOPE_AGENT);
            g1v = __hip_atomic_load(bp + 1, __ATOMIC_RELAXED, __HIP_MEMORY_SCOPE_AGENT);
        }

        // ---- col-max -> private pmax slot (overlaps the granule loads) ----
        cm0 = fmaxf(cm0, __shfl_xor(cm0, 16, 64));
        cm0 = fmaxf(cm0, __shfl_xor(cm0, 32, 64));
        cm1 = fmaxf(cm1, __shfl_xor(cm1, 16, 64));
        cm1 = fmaxf(cm1, __shfl_xor(cm1, 32, 64));
        if (l < 16) {
            unsigned ph = (unsigned)__builtin_bit_cast(unsigned short, (_Float16)cm0)
                        | ((unsigned)__builtin_bit_cast(unsigned short, (_Float16)cm1) << 16);
            pmax[((size_t)b * PS_SLOTS + slotbase + t) * 128 + w * 16 + l] = ph;
        }

        // ---- wave 0: poll tags, land import into DST row 16, ack ----
        if (w == 0 && doImpT) {
            const unsigned tag = (unsigned)(t + 1);
            while ((unsigned)(g0v >> 32) != tag) {
                __builtin_amdgcn_s_sleep(1);
                g0v = __hip_atomic_load(bp, __ATOMIC_RELAXED, __HIP_MEMORY_SCOPE_AGENT);
            }
            while ((unsigned)(g1v >> 32) != tag) {
                __builtin_amdgcn_s_sleep(1);
                g1v = __hip_atomic_load(bp + 1, __ATOMIC_RELAXED, __HIP_MEMORY_SCOPE_AGENT);
            }
            unsigned long long data = (g0v & 0xffffffffull) | (g1v << 32);
            *(unsigned long long*)(lds + (impA ^ rw)) = data;
            if (l == 0)
                __hip_atomic_store(ackP, t + 1, __ATOMIC_RELAXED, __HIP_MEMORY_SCOPE_AGENT);
        }

        LDS_BARRIER();   // END (the only barrier): dst rows + import visible
        rb ^= BUFB;
    }
}

extern "C" void kernel_launch(void* const* d_in, const int* in_sizes, int n_in,
                              void* d_out, int out_size, void* d_ws, size_t ws_size,
                              hipStream_t stream) {
    const float* x  = (const float*)d_in[0];
    const float* Wl = (const float*)d_in[1];
    const float* Wr = (const float*)d_in[2];
    const float* Wb = (const float*)d_in[3];
    const float* Gl = (const float*)d_in[4];
    const float* Gr = (const float*)d_in[5];
    const float* Gb = (const float*)d_in[6];
    float* out = (float*)d_out;
    char* ws = (char*)d_ws;

    _Float16* WT = (_Float16*)ws;                                  // 278,528 B
    unsigned long long* brow = (unsigned long long*)(ws + 278528); // 1,048,576 B (ring 4, tagged)
    int* flags = (int*)(ws + 1327104);                             // 32,768 B (acks)
    unsigned* pmax = (unsigned*)(ws + 1359872);                    // 9,306,112 + 131,072 B

    prep_wt<<<272, 256, 0, stream>>>(Wl, Wr, Gl, Gr, WT);
    init_misc<<<B_, 256, 0, stream>>>(flags, brow);

    void* args[] = { (void*)&x, (void*)&WT, (void*)&Wb, (void*)&Gb,
                     (void*)&pmax, (void*)&brow, (void*)&flags };
    hipLaunchCooperativeKernel((const void*)grcnn_main, dim3(B_ * 8), dim3(NTHR),
                               args, 0, stream);

    decode_out<<<1024, 256, 0, stream>>>(pmax, out);
}

// Round 22
// 321.325 us; speedup vs baseline: 1.4000x; 1.0325x over previous
//
#include <hip/hip_runtime.h>

// GrCNN: B=32, L=128, D=256, 127 sequential levels.
// Round 22: = round 21 (passed, 332us; main 297us) with the import poll
// HIDDEN UNDER THE LEFT K-HALF -- arithmetic bit-identical:
//  The A-fragment spans rows lr..lr+1 ([left|right] concat): STEPs 0-7
//  (k<256) read rows 0..15 only; row 16 is first read at STEP 8. So:
//  - END barrier orders only dst rows 0..15 (import removed from it).
//  - wave 0's first-try granule loads (issued at level-t tail) stay in
//    flight across the barrier; at level t+1 all waves run STEPs 0-7,
//    wave 0 polls (first-try almost always hits now: data ~1600cy old),
//    lands src row 16, acks; BARRIER_A publishes it; STEPs 8-15 proceed.
//  - ack posts one level later (ring-4 slack 3 -> 2 levels, still acyclic).
// Everything else identical to r21: tag-in-data u64 granules, in-wave gate
// MFMA from LDS-staged fragments, fp32 carries, pinned W, one sgbuf
// broadcast, in-main level-0 max, pmax+decode (cw=32w col map).

#define B_ 32
#define L_ 128
#define D_ 256
#define NTHR 512
#define BUFB 16384
#define SGB  9216             // sgbuf: [w][16][3] float = 1536 B (in buf gap)
#define GWT  25088            // gate A-fragments: [16][64]*16B = 16384 B
#define LOG2E 1.4426950408889634f
#define PS_SLOTS 568          // sum_{h=0}^{7} (127-16h)
#define BROW_U64 131072       // 4 slots * 32 b * 8 h * 128 granules (1 MB)

typedef _Float16 half8 __attribute__((ext_vector_type(8)));
typedef float f32x4 __attribute__((ext_vector_type(4)));
typedef unsigned u32x4 __attribute__((ext_vector_type(4)));

#define SWZ(o)  ((o) ^ ((((o) >> 9) & 7) << 4))
#define MFMA16 __builtin_amdgcn_mfma_f32_16x16x32_f16
// LDS-only barrier: no vmcnt drain (granule stores are self-signaling;
// pmax has no intra-kernel consumer; granule loads ride across in flight)
#define LDS_BARRIER() asm volatile("s_waitcnt lgkmcnt(0)\n\ts_barrier" ::: "memory")

// 32-bit-component register pin (r13-verified: stays resident, no remat)
#define PIN(H) { \
    u32x4 t_ = __builtin_bit_cast(u32x4, H); \
    unsigned p0_ = t_[0], p1_ = t_[1], p2_ = t_[2], p3_ = t_[3]; \
    asm volatile("" : "+v"(p0_), "+v"(p1_), "+v"(p2_), "+v"(p3_)); \
    t_[0] = p0_; t_[1] = p1_; t_[2] = p2_; t_[3] = p3_; \
    H = __builtin_bit_cast(half8, t_); }

// ---- WT[272][512] fp16: col j -> 512 k (k<256: Wl/Gl row k, else Wr/Gr) ----
__global__ void prep_wt(const float* __restrict__ Wl, const float* __restrict__ Wr,
                        const float* __restrict__ Gl, const float* __restrict__ Gr,
                        _Float16* __restrict__ WT) {
    int j = blockIdx.x;
    for (int k = threadIdx.x; k < 512; k += 256) {
        float v = 0.f;
        if (j < 256) v = (k < 256) ? Wl[k * 256 + j] : Wr[(k - 256) * 256 + j];
        else { int jj = j - 256; if (jj < 3) v = (k < 256) ? Gl[k * 3 + jj] : Gr[(k - 256) * 3 + jj]; }
        WT[(size_t)j * 512 + k] = (_Float16)v;
    }
}

// ---- init: zero acks + brow only ----
__global__ void init_misc(int* __restrict__ flags, unsigned long long* __restrict__ brow) {
    int b = blockIdx.x, c = threadIdx.x;
    if (b == 0) for (int i = c; i < 2 * 256 * 16; i += 256) flags[i] = 0;
    for (int i = b * 256 + c; i < BROW_U64; i += 32 * 256) brow[i] = 0ull;
}

// ---- decode: pmax/pmax0 partials -> out levels 0..127 (cw=32w col map) ----
__global__ void decode_out(const unsigned* __restrict__ pmax, float* __restrict__ out) {
    const unsigned* pmax0 = pmax + (size_t)32 * PS_SLOTS * 128;  // [b][h][128]
    for (size_t i = (size_t)blockIdx.x * 256 + threadIdx.x; i < (size_t)32 * 128 * 256;
         i += (size_t)gridDim.x * 256) {
        int c = (int)(i & 255);
        int k = (int)((i >> 8) & 127);
        int b = (int)(i / (128 * 256));
        // c = 32w + 16NT + lr -> dw = w*16 + lr, hi = NT
        int dw = ((c >> 5) * 16) + (c & 15);
        int hi = (c >> 4) & 1;
        float mx = -3.4e38f;
        if (k == 0) {
            #pragma unroll
            for (int h = 0; h < 8; ++h) {
                unsigned u = pmax0[((size_t)b * 8 + h) * 128 + dw];
                unsigned short us = hi ? (unsigned short)(u >> 16) : (unsigned short)(u & 0xffff);
                mx = fmaxf(mx, (float)__builtin_bit_cast(_Float16, us));
            }
        } else {
            int hcnt = (143 - k) >> 4;          // ceil((128-k)/16)
            for (int h = 0; h < hcnt; ++h) {
                int slot = 127 * h - 8 * h * (h - 1) + (k - 1);
                unsigned u = pmax[((size_t)b * PS_SLOTS + slot) * 128 + dw];
                unsigned short us = hi ? (unsigned short)(u >> 16) : (unsigned short)(u & 0xffff);
                mx = fmaxf(mx, (float)__builtin_bit_cast(_Float16, us));
            }
        }
        out[((size_t)b * 128 + k) * 256 + c] = mx;
    }
}

__global__ __launch_bounds__(NTHR, 2) void grcnn_main(
    const float* __restrict__ x, const _Float16* __restrict__ WT,
    const float* __restrict__ Wb, const float* __restrict__ Gb,
    unsigned* __restrict__ pmax, unsigned long long* __restrict__ brow,
    int* __restrict__ flags)
{
    __shared__ alignas(16) char lds[GWT + 16384];  // buf0@0, sgbuf@9216, buf1@16384, gwt@25088

    const int tid = threadIdx.x;
    const int b = blockIdx.x & 31, h = blockIdx.x >> 5;
    const int w = tid >> 6, l = tid & 63, lr = l & 15, q = l >> 4;
    const int cw = w * 32;                  // wave's 32-col slab

    // ---- W fragments: 2 col-tiles x 16 ksteps (full K), pinned (128 regs) ----
    const _Float16* wp0 = WT + (size_t)(cw + lr) * 512 + q * 8;
    const _Float16* wp1 = WT + (size_t)(cw + 16 + lr) * 512 + q * 8;
#define LDW(s) \
    half8 WA##s = *(const half8*)(wp0 + s * 32); \
    half8 WB##s = *(const half8*)(wp1 + s * 32); \
    PIN(WA##s) PIN(WB##s)
    LDW(0) LDW(1) LDW(2) LDW(3) LDW(4) LDW(5) LDW(6) LDW(7)
    LDW(8) LDW(9) LDW(10) LDW(11) LDW(12) LDW(13) LDW(14) LDW(15)
#undef LDW

    const float wb0 = Wb[cw + lr], wb1 = Wb[cw + 16 + lr];
    const float gbi0 = Gb[0], gbi1 = Gb[1], gbi2 = Gb[2];

    // ---- precomputed LDS addresses ----
#define RDA(i) const int rd##i = SWZ(lr * 512 + i * 64 + q * 16);
    RDA(0) RDA(1) RDA(2) RDA(3) RDA(4) RDA(5) RDA(6) RDA(7)
    RDA(8) RDA(9) RDA(10) RDA(11) RDA(12) RDA(13) RDA(14) RDA(15)
#undef RDA
    int wo[2][4];
    #pragma unroll
    for (int nt = 0; nt < 2; ++nt)
        #pragma unroll
        for (int r = 0; r < 4; ++r)
            wo[nt][r] = SWZ((q * 4 + r) * 512 + (cw + nt * 16 + lr) * 2);
    const int impA = 8192 + l * 8;               // row 16 (identity swizzle)
    const int bnd0 = 8192 + (cw + lr) * 2;       // boundary u16 (identity swizzle)
    const int bnd1 = 8192 + (cw + 16 + lr) * 2;
    const int sgw = SGB + w * 192;               // this wave's sgbuf slice
    const int gva = GWT + (l << 4);              // gate frag base (stride 1024/kstep)

    int* ackP  = &flags[(256 + b * 8 + h) * 16];
    int* ackC  = &flags[(256 + b * 8 + h - 1) * 16];
    const int slotbase = 127 * h - 8 * h * (h - 1);
    unsigned* pmax0 = pmax + (size_t)32 * PS_SLOTS * 128;

    // ---- stage gate A-fragments once ----
    for (int ch = tid; ch < 1024; ch += NTHR) {
        int i = ch >> 6, ll = ch & 63;
        int llr = ll & 15, lq = ll >> 4;
        half8 v = *(const half8*)(WT + (size_t)(256 + llr) * 512 + i * 32 + lq * 8);
        *(half8*)(lds + GWT + ch * 16) = v;
    }
    // ---- stage rows 16h..16h+16 (clamped) into BOTH buffers ----
    for (int ch = tid; ch < 17 * 32; ch += NTHR) {
        int row = ch >> 5, kc = ch & 31;
        int grow = 16 * h + row; if (grow > 127) grow = 127;
        const float* xp = x + ((size_t)b * L_ + grow) * D_ + kc * 8;
        half8 v;
        #pragma unroll
        for (int j = 0; j < 8; ++j) v[j] = (_Float16)xp[j];
        int off = SWZ(row * 512 + kc * 16);
        *(half8*)(lds + off) = v;
        *(half8*)(lds + BUFB + off) = v;
    }
    __syncthreads();

    // ---- init lv/rv carries from staged state (rows q*4..q*4+3, 2 cols) ----
    float cv0[4], cv1[4];
    #pragma unroll
    for (int i = 0; i < 4; ++i) {
        cv0[i] = (float)*(const _Float16*)(lds + SWZ((q * 4 + i) * 512 + (cw + lr) * 2));
        cv1[i] = (float)*(const _Float16*)(lds + SWZ((q * 4 + i) * 512 + (cw + 16 + lr) * 2));
    }

    // ---- level-0 col-max from carries -> pmax0[b][h] ----
    {
        float c0 = fmaxf(fmaxf(cv0[0], cv0[1]), fmaxf(cv0[2], cv0[3]));
        float c1 = fmaxf(fmaxf(cv1[0], cv1[1]), fmaxf(cv1[2], cv1[3]));
        c0 = fmaxf(c0, __shfl_xor(c0, 16, 64)); c0 = fmaxf(c0, __shfl_xor(c0, 32, 64));
        c1 = fmaxf(c1, __shfl_xor(c1, 16, 64)); c1 = fmaxf(c1, __shfl_xor(c1, 32, 64));
        if (l < 16) {
            unsigned ph = (unsigned)__builtin_bit_cast(unsigned short, (_Float16)c0)
                        | ((unsigned)__builtin_bit_cast(unsigned short, (_Float16)c1) << 16);
            pmax0[((size_t)b * 8 + h) * 128 + w * 16 + l] = ph;
        }
    }

    int rb = 0;   // src base toggle; dst = rb ^ BUFB
    // loop-carried in-flight import state (wave 0)
    unsigned long long g0v = 0, g1v = 0;
    const unsigned long long* bp = nullptr;
    bool pend = false;

    for (int t = 0; t < 127; ++t) {
        const int m = 127 - t - 16 * h;
        if (m <= 0) break;
        const int mm = (m > 16) ? 16 : m;
        const bool doExpN = (h >= 1) && (126 - t >= 16 * h);
        const bool doImpT = (h < 7) && (t <= 110 - 16 * h);
        const int rw = rb ^ BUFB;

        // ---- LEFT K-half: STEPs 0-7 (read src rows 0..15 only) ----
        f32x4 a0 = {}, a1 = {}, ag = {};
#define STEP(i) { \
            half8 av = *(const half8*)(lds + (rd##i ^ rb)); \
            half8 gv = *(const half8*)(lds + gva + i * 1024); \
            a0 = MFMA16(av, WA##i, a0, 0, 0, 0); \
            a1 = MFMA16(av, WB##i, a1, 0, 0, 0); \
            ag = MFMA16(gv, av, ag, 0, 0, 0); }
        STEP(0) STEP(1) STEP(2) STEP(3) STEP(4) STEP(5) STEP(6) STEP(7)

        // ---- wave 0: land pending import (tag == t) into SRC row 16 ----
        if (w == 0 && pend) {
            const unsigned tag = (unsigned)t;
            while ((unsigned)(g0v >> 32) != tag) {
                __builtin_amdgcn_s_sleep(1);
                g0v = __hip_atomic_load(bp, __ATOMIC_RELAXED, __HIP_MEMORY_SCOPE_AGENT);
            }
            while ((unsigned)(g1v >> 32) != tag) {
                __builtin_amdgcn_s_sleep(1);
                g1v = __hip_atomic_load(bp + 1, __ATOMIC_RELAXED, __HIP_MEMORY_SCOPE_AGENT);
            }
            unsigned long long data = (g0v & 0xffffffffull) | (g1v << 32);
            *(unsigned long long*)(lds + (impA ^ rb)) = data;
            if (l == 0)
                __hip_atomic_store(ackP, t, __ATOMIC_RELAXED, __HIP_MEMORY_SCOPE_AGENT);
        }
        LDS_BARRIER();   // A: src row 16 published before the right K-half

        // ---- RIGHT K-half: STEPs 8-15 (read src rows 1..16) ----
        STEP(8) STEP(9) STEP(10) STEP(11) STEP(12) STEP(13) STEP(14) STEP(15)
#undef STEP

        // ---- in-lane softmax (lanes 0..15 hold complete preacts) -> sgbuf ----
        if (l < 16) {
            float p0 = ag[0] + gbi0, p1 = ag[1] + gbi1, p2 = ag[2] + gbi2;
            float mg = fmaxf(fmaxf(p0, p1), p2);
            float ee0 = __builtin_amdgcn_exp2f((p0 - mg) * LOG2E);
            float ee1 = __builtin_amdgcn_exp2f((p1 - mg) * LOG2E);
            float ee2 = __builtin_amdgcn_exp2f((p2 - mg) * LOG2E);
            float inv = __builtin_amdgcn_rcpf(ee0 + ee1 + ee2);
            float* sp = (float*)(lds + sgw + l * 12);
            sp[0] = ee0 * inv; sp[1] = ee1 * inv; sp[2] = ee2 * inv;
        }
        // within-wave ordering: sgbuf writes complete before broadcast reads
        asm volatile("s_waitcnt lgkmcnt(0)" ::: "memory");
        __builtin_amdgcn_sched_barrier(0);
        // broadcast read: rows q*4..q*4+3, 3 gates each (48B, same addr per group)
        f32x4 v0 = *(const f32x4*)(lds + sgw + q * 48);
        f32x4 v1 = *(const f32x4*)(lds + sgw + q * 48 + 16);
        f32x4 v2 = *(const f32x4*)(lds + sgw + q * 48 + 32);
        float g0a[4] = { v0[0], v0[3], v1[2], v2[1] };
        float g1a[4] = { v0[1], v1[0], v1[3], v2[2] };
        float g2a[4] = { v0[2], v1[1], v2[0], v2[3] };

        // ---- boundary rv (row 16, fp16) + next-q-group row-0 carry (fp32) ----
        float b0 = (float)*(const _Float16*)(lds + (bnd0 ^ rb));
        float b1 = (float)*(const _Float16*)(lds + (bnd1 ^ rb));
        float s0 = __shfl(cv0[0], (l + 16) & 63, 64);
        float s1 = __shfl(cv1[0], (l + 16) & 63, 64);

        // ---- export-slot reuse gate (ring depth 4), post-MFMA ----
        if (doExpN && t >= 3 && l == 0) {
            while (__hip_atomic_load(ackC, __ATOMIC_RELAXED, __HIP_MEMORY_SCOPE_AGENT) < t - 3)
                __builtin_amdgcn_s_sleep(1);
        }

        // ---- epilogue (exports = self-signaling tagged u64 granules) ----
        const unsigned long long tagv = (unsigned long long)(t + 1) << 32;
        float cm0 = -3.4e38f, cm1 = -3.4e38f;
        #pragma unroll
        for (int r = 0; r < 4; ++r) {
            const int row = q * 4 + r;
            float g0f = g0a[r];
            float g1f = g1a[r];
            float g2f = g2a[r];
            if (row < mm) {
                #define EPI(NT, ACC, CV, SHV, BV, WBV, CMV) {                                \
                    float pre = ACC[r] + WBV;                                                \
                    float exx = __builtin_amdgcn_exp2f(pre * (2.f * LOG2E));                 \
                    float ce = 1.f - 2.f * __builtin_amdgcn_rcpf(exx + 1.f);                 \
                    float lv = CV[r];                                                        \
                    float rv = (r < 3) ? CV[(r < 3) ? r + 1 : 0] : (q < 3 ? SHV : BV);       \
                    float nx = g0f * lv + g1f * ce + g2f * rv;                               \
                    CMV = fmaxf(CMV, nx);                                                    \
                    _Float16 nh = (_Float16)nx;                                              \
                    CV[r] = nx;   /* FP32 carry: no per-level rounding */                    \
                    int pdi = __builtin_amdgcn_update_dpp(                                   \
                        0, __builtin_bit_cast(int, nx), 0xB1, 0xF, 0xF, true);               \
                    float pnx = __builtin_bit_cast(float, pdi);                              \
                    unsigned pk = (unsigned)__builtin_bit_cast(unsigned short, nh)           \
                        | ((unsigned)__builtin_bit_cast(unsigned short, (_Float16)pnx) << 16);\
                    if (!(lr & 1)) {                                                         \
                        *(unsigned*)(lds + (wo[NT][r] ^ rw)) = pk;                           \
                        if (r == 0 && q == 0 && doExpN) {                                    \
                            unsigned long long* ep = brow +                                  \
                                (((size_t)((t + 1) & 3) * 32 + b) * 8 + h) * 128             \
                                + (cw >> 1) + NT * 8 + (lr >> 1);                            \
                            __hip_atomic_store(ep, (unsigned long long)pk | tagv,            \
                                               __ATOMIC_RELAXED, __HIP_MEMORY_SCOPE_AGENT);  \
                        }                                                                    \
                    }                                                                        \
                }
                EPI(0, a0, cv0, s0, b0, wb0, cm0)
                EPI(1, a1, cv1, s1, b1, wb1, cm1)
                #undef EPI
            }
        }

        // ---- wave 0: issue first-try granule loads for level t+1 boundary ----
        if (w == 0 && doImpT) {
            bp = brow + (((size_t)((t + 1) & 3) * 32 + b) * 8 + (h + 1)) * 128 + 2 * l;
            g0v = __hip_atomic_load(bp,     __ATOMIC_RELAXED, __HIP_MEMORY_SCOPE_AGENT);
            g1v = __hip_atomic_load(bp + 1, __ATOMIC_RELAXED, __HIP_MEMORY_SCOPE_AGENT);
        }
        pend = doImpT;

        // ---- col-max -> private pmax slot (overlaps the granule loads) ----
        cm0 = fmaxf(cm0, __shfl_xor(cm0, 16, 64));
        cm0 = fmaxf(cm0, __shfl_xor(cm0, 32, 64));
        cm1 = fmaxf(cm1, __shfl_xor(cm1, 16, 64));
        cm1 = fmaxf(cm1, __shfl_xor(cm1, 32, 64));
        if (l < 16) {
            unsigned ph = (unsigned)__builtin_bit_cast(unsigned short, (_Float16)cm0)
                        | ((unsigned)__builtin_bit_cast(unsigned short, (_Float16)cm1) << 16);
            pmax[((size_t)b * PS_SLOTS + slotbase + t) * 128 + w * 16 + l] = ph;
        }

        LDS_BARRIER();   // END: dst rows 0..15 visible (import NOT required)
        rb ^= BUFB;
    }
}

extern "C" void kernel_launch(void* const* d_in, const int* in_sizes, int n_in,
                              void* d_out, int out_size, void* d_ws, size_t ws_size,
                              hipStream_t stream) {
    const float* x  = (const float*)d_in[0];
    const float* Wl = (const float*)d_in[1];
    const float* Wr = (const float*)d_in[2];
    const float* Wb = (const float*)d_in[3];
    const float* Gl = (const float*)d_in[4];
    const float* Gr = (const float*)d_in[5];
    const float* Gb = (const float*)d_in[6];
    float* out = (float*)d_out;
    char* ws = (char*)d_ws;

    _Float16* WT = (_Float16*)ws;                                  // 278,528 B
    unsigned long long* brow = (unsigned long long*)(ws + 278528); // 1,048,576 B (ring 4, tagged)
    int* flags = (int*)(ws + 1327104);                             // 32,768 B (acks)
    unsigned* pmax = (unsigned*)(ws + 1359872);                    // 9,306,112 + 131,072 B

    prep_wt<<<272, 256, 0, stream>>>(Wl, Wr, Gl, Gr, WT);
    init_misc<<<B_, 256, 0, stream>>>(flags, brow);

    void* args[] = { (void*)&x, (void*)&WT, (void*)&Wb, (void*)&Gb,
                     (void*)&pmax, (void*)&brow, (void*)&flags };
    hipLaunchCooperativeKernel((const void*)grcnn_main, dim3(B_ * 8), dim3(NTHR),
                               args, 0, stream);

    decode_out<<<1024, 256, 0, stream>>>(pmax, out);
}